// Round 1
// baseline (1012.938 us; speedup 1.0000x reference)
//
#include <hip/hip_runtime.h>
#include <math.h>

// Problem constants: B=2, T=2048, C=1024, H=16, hd=64
#define SEQ_T 2048
#define CDIM 1024
#define HD 64
#define NH 16
#define NB 2
#define BH (NB * NH)          // 32
#define MROWS (NB * SEQ_T)    // 4096

// ---------------------------------------------------------------------------
// RoPE tables: cos[t][d] = cos(t * inv_freq[d % 32]), inv_freq[i] = 10000^(-2i/64)
// Matches reference: concat([cos(freqs), cos(freqs)], -1), interleaved rotate_half.
// ---------------------------------------------------------------------------
__global__ void rope_table_kernel(float* __restrict__ cosT, float* __restrict__ sinT) {
    const int t = blockIdx.x;
    const int d = threadIdx.x;          // 0..63
    const int i = d & 31;
    const float inv = powf(10000.0f, -((float)(2 * i) / 64.0f));
    const float f = (float)t * inv;
    cosT[t * HD + d] = cosf(f);
    sinT[t * HD + d] = sinf(f);
}

// ---------------------------------------------------------------------------
// Tiled fp32 GEMM: Y[m][n] = sum_k A[m][k] * W[n][k] + bias[n]
// 64x64 tile, BK=16, 256 threads, 4x4 micro-tile per thread.
// ROPE=1: epilogue decodes n -> (mat,h,d), applies RoPE to Q/K, scatters to
//         Qo/Ko/Vo in [B][H][T][hd] layout.
// ROPE=0: writes Y row-major [M][N].
// ---------------------------------------------------------------------------
template <int ROPE>
__global__ __launch_bounds__(256) void gemm_kernel(
    const float* __restrict__ A,     // [M][K]
    const float* __restrict__ W,     // [N][K]
    const float* __restrict__ bias,  // [N]
    const float* __restrict__ cosT,
    const float* __restrict__ sinT,
    float* __restrict__ Qo, float* __restrict__ Ko, float* __restrict__ Vo,
    float* __restrict__ Yo,
    int M, int N, int K)
{
    __shared__ float As[16][68];   // [k][m], padded
    __shared__ float Bs[16][68];   // [k][n], padded

    const int tid  = threadIdx.x;
    const int row0 = blockIdx.x * 64;
    const int col0 = blockIdx.y * 64;

    // loader: each thread loads one float4 along K for one row of A and W
    const int lm  = tid >> 2;          // 0..63
    const int lk4 = (tid & 3) << 2;    // 0,4,8,12

    // compute: 16x16 thread grid, 4 rows x 4 cols each
    const int tr = (tid >> 4) << 2;
    const int tc = (tid & 15) << 2;

    const float* Arow = A + (size_t)(row0 + lm) * K + lk4;
    const float* Wrow = W + (size_t)(col0 + lm) * K + lk4;

    float acc[4][4] = {};

    for (int k0 = 0; k0 < K; k0 += 16) {
        const float4 av = *(const float4*)(Arow + k0);
        const float4 bv = *(const float4*)(Wrow + k0);
        __syncthreads();   // previous iteration's reads complete
        As[lk4 + 0][lm] = av.x; As[lk4 + 1][lm] = av.y;
        As[lk4 + 2][lm] = av.z; As[lk4 + 3][lm] = av.w;
        Bs[lk4 + 0][lm] = bv.x; Bs[lk4 + 1][lm] = bv.y;
        Bs[lk4 + 2][lm] = bv.z; Bs[lk4 + 3][lm] = bv.w;
        __syncthreads();
        #pragma unroll
        for (int kk = 0; kk < 16; ++kk) {
            const float4 a4 = *(const float4*)&As[kk][tr];
            const float4 b4 = *(const float4*)&Bs[kk][tc];
            const float a_[4] = {a4.x, a4.y, a4.z, a4.w};
            const float b_[4] = {b4.x, b4.y, b4.z, b4.w};
            #pragma unroll
            for (int i = 0; i < 4; ++i)
                #pragma unroll
                for (int j = 0; j < 4; ++j)
                    acc[i][j] = fmaf(a_[i], b_[j], acc[i][j]);
        }
    }

    if (ROPE) {
        #pragma unroll
        for (int i = 0; i < 4; ++i) {
            const int m = row0 + tr + i;
            const int b = m >> 11;
            const int t = m & (SEQ_T - 1);
            #pragma unroll
            for (int j0 = 0; j0 < 4; j0 += 2) {
                const int n  = col0 + tc + j0;
                float v0 = acc[i][j0]     + bias[n];
                float v1 = acc[i][j0 + 1] + bias[n + 1];
                const int mat = n >> 10;        // 0=Q 1=K 2=V
                const int h   = (n >> 6) & 15;
                const int d   = n & 63;         // even
                const size_t idx = (((size_t)(b * NH + h) * SEQ_T) + t) * HD + d;
                if (mat == 2) {
                    Vo[idx]     = v0;
                    Vo[idx + 1] = v1;
                } else {
                    const float c0 = cosT[t * HD + d],     s0 = sinT[t * HD + d];
                    const float c1 = cosT[t * HD + d + 1], s1 = sinT[t * HD + d + 1];
                    const float r0 = v0 * c0 - v1 * s0;   // even: q*cos - q_odd*sin
                    const float r1 = v1 * c1 + v0 * s1;   // odd:  q*cos + q_even*sin
                    float* dst = (mat == 0) ? Qo : Ko;
                    dst[idx]     = r0;
                    dst[idx + 1] = r1;
                }
            }
        }
    } else {
        #pragma unroll
        for (int i = 0; i < 4; ++i) {
            const int m = row0 + tr + i;
            float4 ov;
            ov.x = acc[i][0] + bias[col0 + tc + 0];
            ov.y = acc[i][1] + bias[col0 + tc + 1];
            ov.z = acc[i][2] + bias[col0 + tc + 2];
            ov.w = acc[i][3] + bias[col0 + tc + 3];
            *(float4*)&Yo[(size_t)m * N + col0 + tc] = ov;
        }
    }
}

// ---------------------------------------------------------------------------
// Flash-style causal attention, fp32.
// Grid: (qt=32, bh=32). Block: 256 threads. 64-query tile; K/V 64-tiles.
// Q/K stored transposed in LDS ([d][row]) for float4 fragment reads.
// Online softmax, 16-lane row groups reduced via __shfl_xor.
// Output written to [B][T][C] layout (= transpose(0,2,1,3).reshape).
// ---------------------------------------------------------------------------
__global__ __launch_bounds__(256) void attn_kernel(
    const float* __restrict__ Q,   // [BH][T][hd]
    const float* __restrict__ K,
    const float* __restrict__ V,
    float* __restrict__ O)         // [B][T][C]
{
    __shared__ float Qs[64][68];   // [d][r]
    __shared__ float Ks[64][68];   // [d][c]
    __shared__ float Vs[64][68];   // [k][d]
    __shared__ float Ps[64][68];   // [k][r]

    const int qt  = blockIdx.x;
    const int bh  = blockIdx.y;
    const int tid = threadIdx.x;

    const int lr  = tid >> 2;          // 0..63 (tile row for loads)
    const int ld4 = (tid & 3) << 2;    // 0,4,8,12 -> *4 floats along d... (16 floats/row in 4 groups)
    const int tr  = (tid >> 4) << 2;   // compute rows
    const int tc  = (tid & 15) << 2;   // compute cols

    const float* Qb = Q + (size_t)bh * SEQ_T * HD;
    const float* Kb = K + (size_t)bh * SEQ_T * HD;
    const float* Vb = V + (size_t)bh * SEQ_T * HD;

    // load Q tile (transposed into LDS); 4 float4 per thread covers 64x64
    #pragma unroll
    for (int rep = 0; rep < 4; ++rep) {
        const int d0 = ld4 + rep * 16;
        const float4 qv = *(const float4*)&Qb[(size_t)(qt * 64 + lr) * HD + d0];
        Qs[d0 + 0][lr] = qv.x; Qs[d0 + 1][lr] = qv.y;
        Qs[d0 + 2][lr] = qv.z; Qs[d0 + 3][lr] = qv.w;
    }

    float m_i[4], l_i[4], o[4][4];
    #pragma unroll
    for (int i = 0; i < 4; ++i) {
        m_i[i] = -1e30f; l_i[i] = 0.0f;
        #pragma unroll
        for (int j = 0; j < 4; ++j) o[i][j] = 0.0f;
    }

    for (int kt = 0; kt <= qt; ++kt) {
        __syncthreads();   // previous tile's Ks/Vs/Ps reads complete
        #pragma unroll
        for (int rep = 0; rep < 4; ++rep) {
            const int d0 = ld4 + rep * 16;
            const float4 kv = *(const float4*)&Kb[(size_t)(kt * 64 + lr) * HD + d0];
            Ks[d0 + 0][lr] = kv.x; Ks[d0 + 1][lr] = kv.y;
            Ks[d0 + 2][lr] = kv.z; Ks[d0 + 3][lr] = kv.w;
            const float4 vv = *(const float4*)&Vb[(size_t)(kt * 64 + lr) * HD + d0];
            *(float4*)&Vs[lr][d0] = vv;
        }
        __syncthreads();

        // S = Q K^T (4x4 per thread)
        float s[4][4] = {};
        #pragma unroll 8
        for (int d = 0; d < 64; ++d) {
            const float4 a4 = *(const float4*)&Qs[d][tr];
            const float4 b4 = *(const float4*)&Ks[d][tc];
            const float a_[4] = {a4.x, a4.y, a4.z, a4.w};
            const float b_[4] = {b4.x, b4.y, b4.z, b4.w};
            #pragma unroll
            for (int i = 0; i < 4; ++i)
                #pragma unroll
                for (int j = 0; j < 4; ++j)
                    s[i][j] = fmaf(a_[i], b_[j], s[i][j]);
        }

        // causal mask + scale + online softmax (16-lane row groups)
        const int rg0 = qt * 64 + tr;
        const int cg0 = kt * 64 + tc;
        #pragma unroll
        for (int i = 0; i < 4; ++i) {
            const int rg = rg0 + i;
            float mx = -1e30f;
            #pragma unroll
            for (int j = 0; j < 4; ++j) {
                const float sv = (cg0 + j <= rg) ? s[i][j] * 0.125f : -1e30f;
                s[i][j] = sv;
                mx = fmaxf(mx, sv);
            }
            mx = fmaxf(mx, __shfl_xor(mx, 1, 16));
            mx = fmaxf(mx, __shfl_xor(mx, 2, 16));
            mx = fmaxf(mx, __shfl_xor(mx, 4, 16));
            mx = fmaxf(mx, __shfl_xor(mx, 8, 16));
            const float mnew  = fmaxf(m_i[i], mx);
            const float alpha = __expf(m_i[i] - mnew);
            float p[4], rs = 0.0f;
            #pragma unroll
            for (int j = 0; j < 4; ++j) { p[j] = __expf(s[i][j] - mnew); rs += p[j]; }
            rs += __shfl_xor(rs, 1, 16);
            rs += __shfl_xor(rs, 2, 16);
            rs += __shfl_xor(rs, 4, 16);
            rs += __shfl_xor(rs, 8, 16);
            l_i[i] = l_i[i] * alpha + rs;
            m_i[i] = mnew;
            #pragma unroll
            for (int j = 0; j < 4; ++j) {
                o[i][j] *= alpha;
                Ps[tc + j][tr + i] = p[j];   // P transposed: [k][r]
            }
        }
        __syncthreads();

        // O += P V
        #pragma unroll 8
        for (int kk = 0; kk < 64; ++kk) {
            const float4 pa = *(const float4*)&Ps[kk][tr];
            const float4 va = *(const float4*)&Vs[kk][tc];
            const float p_[4] = {pa.x, pa.y, pa.z, pa.w};
            const float v_[4] = {va.x, va.y, va.z, va.w};
            #pragma unroll
            for (int i = 0; i < 4; ++i)
                #pragma unroll
                for (int j = 0; j < 4; ++j)
                    o[i][j] = fmaf(p_[i], v_[j], o[i][j]);
        }
    }

    // epilogue: normalize and write [B][T][C]
    const int b = bh >> 4;
    const int h = bh & 15;
    #pragma unroll
    for (int i = 0; i < 4; ++i) {
        const int t = qt * 64 + tr + i;
        const float inv = 1.0f / l_i[i];
        float4 ov;
        ov.x = o[i][0] * inv; ov.y = o[i][1] * inv;
        ov.z = o[i][2] * inv; ov.w = o[i][3] * inv;
        *(float4*)&O[((size_t)(b * SEQ_T + t)) * CDIM + h * HD + tc] = ov;
    }
}

// ---------------------------------------------------------------------------
extern "C" void kernel_launch(void* const* d_in, const int* in_sizes, int n_in,
                              void* d_out, int out_size, void* d_ws, size_t ws_size,
                              hipStream_t stream) {
    (void)in_sizes; (void)n_in; (void)out_size; (void)ws_size;

    const float* x    = (const float*)d_in[0];
    // d_in[1] = mask (int32) — causal structure is known, unused
    const float* Wqkv = (const float*)d_in[2];
    const float* bqkv = (const float*)d_in[3];
    const float* Wo   = (const float*)d_in[4];
    const float* bo   = (const float*)d_in[5];
    float* out = (float*)d_out;

    float* ws   = (float*)d_ws;
    float* cosT = ws;                        // 2048*64
    float* sinT = cosT + SEQ_T * HD;         // 2048*64
    float* Qw   = sinT + SEQ_T * HD;         // 32*2048*64 = 4.19M
    float* Kw   = Qw + (size_t)BH * SEQ_T * HD;
    float* Vw   = Kw + (size_t)BH * SEQ_T * HD;
    float* AO   = Vw + (size_t)BH * SEQ_T * HD;  // [B][T][C]

    rope_table_kernel<<<SEQ_T, HD, 0, stream>>>(cosT, sinT);

    // QKV projection + bias + RoPE scatter: M=4096, N=3072, K=1024
    gemm_kernel<1><<<dim3(MROWS / 64, 3 * CDIM / 64), 256, 0, stream>>>(
        x, Wqkv, bqkv, cosT, sinT, Qw, Kw, Vw, nullptr, MROWS, 3 * CDIM, CDIM);

    // causal flash attention
    attn_kernel<<<dim3(SEQ_T / 64, BH), 256, 0, stream>>>(Qw, Kw, Vw, AO);

    // output projection: M=4096, N=1024, K=1024
    gemm_kernel<0><<<dim3(MROWS / 64, CDIM / 64), 256, 0, stream>>>(
        AO, Wo, bo, nullptr, nullptr, nullptr, nullptr, nullptr, out, MROWS, CDIM, CDIM);
}

// Round 4
// 571.907 us; speedup vs baseline: 1.7712x; 1.7712x over previous
//
#include <hip/hip_runtime.h>
#include <math.h>

// Problem constants: B=2, T=2048, C=1024, H=16, hd=64
#define SEQ_T 2048
#define CDIM 1024
#define HD 64
#define NH 16
#define NB 2
#define BH (NB * NH)          // 32
#define MROWS (NB * SEQ_T)    // 4096

typedef __attribute__((ext_vector_type(8))) short bf16x8;
typedef __attribute__((ext_vector_type(4))) float f32x4;

__device__ inline short f2bf(float f) {
    unsigned u = __float_as_uint(f);
    u += 0x7fff + ((u >> 16) & 1);          // RNE to bf16
    return (short)(u >> 16);
}
__device__ inline float bf2f(short s) {
    return __uint_as_float(((unsigned)(unsigned short)s) << 16);
}
__device__ inline void split1(float f, short& h, short& l) {
    h = f2bf(f);
    l = f2bf(f - bf2f(h));
}
__device__ inline void split8(const float* f, bf16x8& hi, bf16x8& lo) {
    #pragma unroll
    for (int i = 0; i < 8; ++i) {
        short h, l;
        split1(f[i], h, l);
        hi[i] = h; lo[i] = l;
    }
}

// ---------------------------------------------------------------------------
// RoPE tables: cos[t][d] = cos(t * inv_freq[d%32]), inv_freq[i]=10000^(-2i/64)
// (reference: concat'd table indexed d%32, interleaved rotate_half)
// ---------------------------------------------------------------------------
__global__ void rope_table_kernel(float* __restrict__ cosT, float* __restrict__ sinT) {
    const int t = blockIdx.x;
    const int d = threadIdx.x;          // 0..63
    const int i = d & 31;
    const float inv = powf(10000.0f, -((float)(2 * i) / 64.0f));
    const float f = (float)t * inv;
    cosT[t * HD + d] = cosf(f);
    sinT[t * HD + d] = sinf(f);
}

// ---------------------------------------------------------------------------
// fp32 -> bf16 hi/lo pre-split (memory-bound)
// ---------------------------------------------------------------------------
__global__ __launch_bounds__(256) void split_kernel(
    const float* __restrict__ in, short* __restrict__ hi, short* __restrict__ lo, int n8)
{
    for (int i = blockIdx.x * blockDim.x + threadIdx.x; i < n8; i += gridDim.x * blockDim.x) {
        float fv[8];
        *(float4*)&fv[0] = *(const float4*)(in + (size_t)i * 8);
        *(float4*)&fv[4] = *(const float4*)(in + (size_t)i * 8 + 4);
        bf16x8 h, l;
        split8(fv, h, l);
        ((bf16x8*)hi)[i] = h;
        ((bf16x8*)lo)[i] = l;
    }
}

// ---------------------------------------------------------------------------
// bf16x3 MFMA GEMM: Y[m][n] = sum_k A[m][k]*W[n][k] + bias[n]
// A,W pre-split bf16 hi/lo. 64x128 tile, BK=32, 4 waves (2x2), wave = 32x64
// (2x4 fragments of 16x16x32). A/B frags use the SAME k-map (k=8g+i) so any
// hw k-permutation cancels. C/D (m89): col=lane&15, row=4*(lane>>4)+reg.
// PART 0/1/2 (Q/K/V): epilogue adds bias, RoPE for Q/K (partner via
//   shfl_xor 1), K scaled 0.125, writes bf16 hi/lo at [B*H][T][hd].
// PART 3: writes fp32 Y + bias (out projection).
// ---------------------------------------------------------------------------
template <int PART>
__global__ __launch_bounds__(256) void gemm_mfma_kernel(
    const short* __restrict__ Ahg, const short* __restrict__ Alg,   // [M][K]
    const short* __restrict__ Bhg, const short* __restrict__ Blg,   // [N][K]
    const float* __restrict__ bias,
    const float* __restrict__ cosT, const float* __restrict__ sinT,
    short* __restrict__ Ph, short* __restrict__ Pl,   // PART 0..2 target
    float* __restrict__ Yo,                           // PART 3 target
    int M, int N, int K)
{
    __shared__ short As_h[64][40],  As_l[64][40];    // [m][k], pad 40
    __shared__ short Bs_h[128][40], Bs_l[128][40];   // [n][k]

    const int tid  = threadIdx.x;
    const int row0 = blockIdx.x * 64;
    const int col0 = blockIdx.y * 128;
    const int lane = tid & 63;
    const int w    = tid >> 6;
    const int wr   = (w >> 1) * 32;     // wave 2x2 grid: 32 rows x 64 cols
    const int wc   = (w & 1) * 64;
    const int g    = lane >> 4;         // k-group: holds k = 8g..8g+7
    const int c    = lane & 15;

    // staging: thread covers A row r0 (32 cols via col8) and B rows r0, r0+64
    const int r0   = tid >> 2;          // 0..63
    const int col8 = (tid & 3) * 8;     // 0,8,16,24

    const short* pAh = Ahg + (size_t)(row0 + r0) * K + col8;
    const short* pAl = Alg + (size_t)(row0 + r0) * K + col8;
    const short* pBh0 = Bhg + (size_t)(col0 + r0) * K + col8;
    const short* pBh1 = pBh0 + (size_t)64 * K;
    const short* pBl0 = Blg + (size_t)(col0 + r0) * K + col8;
    const short* pBl1 = pBl0 + (size_t)64 * K;

    const f32x4 fz = {0.f, 0.f, 0.f, 0.f};
    f32x4 acc[2][4];
    #pragma unroll
    for (int i = 0; i < 2; ++i)
        #pragma unroll
        for (int j = 0; j < 4; ++j)
            acc[i][j] = fz;

    // prologue: k0=0 staging regs
    bf16x8 sa_h, sa_l, sb_h0, sb_h1, sb_l0, sb_l1;
    sa_h  = *(const bf16x8*)(pAh);
    sa_l  = *(const bf16x8*)(pAl);
    sb_h0 = *(const bf16x8*)(pBh0);
    sb_h1 = *(const bf16x8*)(pBh1);
    sb_l0 = *(const bf16x8*)(pBl0);
    sb_l1 = *(const bf16x8*)(pBl1);

    for (int k0 = 0; k0 < K; k0 += 32) {
        __syncthreads();   // previous iteration's frag reads complete
        *(bf16x8*)&As_h[r0][col8]      = sa_h;
        *(bf16x8*)&As_l[r0][col8]      = sa_l;
        *(bf16x8*)&Bs_h[r0][col8]      = sb_h0;
        *(bf16x8*)&Bs_h[r0 + 64][col8] = sb_h1;
        *(bf16x8*)&Bs_l[r0][col8]      = sb_l0;
        *(bf16x8*)&Bs_l[r0 + 64][col8] = sb_l1;
        if (k0 + 32 < K) {   // prefetch next K-slab (hides latency under MFMA)
            const int kn = k0 + 32;
            sa_h  = *(const bf16x8*)(pAh + kn);
            sa_l  = *(const bf16x8*)(pAl + kn);
            sb_h0 = *(const bf16x8*)(pBh0 + kn);
            sb_h1 = *(const bf16x8*)(pBh1 + kn);
            sb_l0 = *(const bf16x8*)(pBl0 + kn);
            sb_l1 = *(const bf16x8*)(pBl1 + kn);
        }
        __syncthreads();

        bf16x8 afh[2], afl[2], bfh[4], bfl[4];
        #pragma unroll
        for (int am = 0; am < 2; ++am) {
            afh[am] = *(const bf16x8*)&As_h[wr + 16 * am + c][8 * g];
            afl[am] = *(const bf16x8*)&As_l[wr + 16 * am + c][8 * g];
        }
        #pragma unroll
        for (int bn = 0; bn < 4; ++bn) {
            bfh[bn] = *(const bf16x8*)&Bs_h[wc + 16 * bn + c][8 * g];
            bfl[bn] = *(const bf16x8*)&Bs_l[wc + 16 * bn + c][8 * g];
        }
        #pragma unroll
        for (int am = 0; am < 2; ++am)
            #pragma unroll
            for (int bn = 0; bn < 4; ++bn) {
                acc[am][bn] = __builtin_amdgcn_mfma_f32_16x16x32_bf16(afh[am], bfh[bn], acc[am][bn], 0, 0, 0);
                acc[am][bn] = __builtin_amdgcn_mfma_f32_16x16x32_bf16(afl[am], bfh[bn], acc[am][bn], 0, 0, 0);
                acc[am][bn] = __builtin_amdgcn_mfma_f32_16x16x32_bf16(afh[am], bfl[bn], acc[am][bn], 0, 0, 0);
            }
    }

    if (PART < 3) {
        // n in [0, 1024): h = n>>6, d = n&63. C/D: row=4g+r, col=c.
        #pragma unroll
        for (int am = 0; am < 2; ++am) {
            #pragma unroll
            for (int bn = 0; bn < 4; ++bn) {
                const int n = col0 + wc + 16 * bn + c;
                const int h = n >> 6;
                const int d = n & 63;
                const float bsv = bias[n];
                #pragma unroll
                for (int r = 0; r < 4; ++r) {
                    const int m = row0 + wr + 16 * am + 4 * g + r;
                    const int b = m >> 11;
                    const int t = m & (SEQ_T - 1);
                    const float v  = acc[am][bn][r] + bsv;
                    const float vp = __shfl_xor(v, 1, 16);   // partner col n^1, same row
                    float rv;
                    if (PART == 2) {
                        rv = v;
                    } else {
                        const float cs = cosT[t * HD + d], sn = sinT[t * HD + d];
                        rv = (d & 1) ? (v * cs + vp * sn) : (v * cs - vp * sn);
                    }
                    if (PART == 1) rv *= 0.125f;   // fold 1/sqrt(hd) into K
                    short hi, lo;
                    split1(rv, hi, lo);
                    const size_t idx = (((size_t)(b * NH + h) * SEQ_T) + t) * HD + d;
                    Ph[idx] = hi;
                    Pl[idx] = lo;
                }
            }
        }
    } else {
        #pragma unroll
        for (int am = 0; am < 2; ++am)
            #pragma unroll
            for (int bn = 0; bn < 4; ++bn) {
                const int n = col0 + wc + 16 * bn + c;
                const float bsv = bias[n];
                #pragma unroll
                for (int r = 0; r < 4; ++r) {
                    const int m = row0 + wr + 16 * am + 4 * g + r;
                    Yo[(size_t)m * N + n] = acc[am][bn][r] + bsv;
                }
            }
    }
}

// ---------------------------------------------------------------------------
// MFMA flash attention. Inputs pre-split bf16 hi/lo (K pre-scaled by 1/8).
// Grid (qt=32, bh=32), 4 waves, each wave a 16-row Q strip (offset w*16).
// Q/K frags direct from global (L2-resident); V staged transposed in LDS as
// bf16 hi/lo (paired-key u32 writes); P relayout through per-wave LDS.
// Output written pre-split bf16 hi/lo for the out-projection.
// ---------------------------------------------------------------------------
__global__ __launch_bounds__(256) void attn_mfma_kernel(
    const short* __restrict__ Qh, const short* __restrict__ Ql,
    const short* __restrict__ Kh, const short* __restrict__ Kl,
    const short* __restrict__ Vh, const short* __restrict__ Vl,
    short* __restrict__ AOh, short* __restrict__ AOl)
{
    __shared__ short Vth[64][72];      // [d][key] hi
    __shared__ short Vtl[64][72];      // [d][key] lo
    __shared__ float Pw[4][16][68];    // per-wave P strip [row][key]

    const int qt  = blockIdx.x;
    const int bh  = blockIdx.y;
    const int tid = threadIdx.x;
    const int w    = tid >> 6;
    const int lane = tid & 63;
    const int g    = lane >> 4;        // k-group
    const int c    = lane & 15;

    const size_t base = (size_t)bh * SEQ_T * HD;

    // Q fragments: rows qt*64 + w*16 + c
    bf16x8 qfh[2], qfl[2];
    {
        const short* qrh = Qh + base + (size_t)(qt * 64 + w * 16 + c) * HD;
        const short* qrl = Ql + base + (size_t)(qt * 64 + w * 16 + c) * HD;
        #pragma unroll
        for (int kh = 0; kh < 2; ++kh) {
            qfh[kh] = *(const bf16x8*)(qrh + kh * 32 + 8 * g);
            qfl[kh] = *(const bf16x8*)(qrl + kh * 32 + 8 * g);
        }
    }

    const f32x4 fz = {0.f, 0.f, 0.f, 0.f};
    f32x4 o_acc[4];
    float m_i[4], l_i[4];
    #pragma unroll
    for (int r = 0; r < 4; ++r) { o_acc[r] = fz; m_i[r] = -1e30f; l_i[r] = 0.f; }

    // V staging map: kp = key-pair 0..31, dseg = d-chunk 0..7
    const int kp   = tid & 31;
    const int dseg = tid >> 5;

    for (int kt = 0; kt <= qt; ++kt) {
        const int kb = kt * 64;

        // prefetch V (keys 2kp, 2kp+1; d = dseg*8..+7), hi+lo
        bf16x8 v0h = *(const bf16x8*)(Vh + base + (size_t)(kb + 2 * kp) * HD + dseg * 8);
        bf16x8 v1h = *(const bf16x8*)(Vh + base + (size_t)(kb + 2 * kp + 1) * HD + dseg * 8);
        bf16x8 v0l = *(const bf16x8*)(Vl + base + (size_t)(kb + 2 * kp) * HD + dseg * 8);
        bf16x8 v1l = *(const bf16x8*)(Vl + base + (size_t)(kb + 2 * kp + 1) * HD + dseg * 8);

        __syncthreads();   // barrier A: prior iteration's Vt/Pw reads complete

        #pragma unroll
        for (int j = 0; j < 8; ++j) {
            const int d = dseg * 8 + j;
            const unsigned ph = (unsigned)(unsigned short)v0h[j] | ((unsigned)(unsigned short)v1h[j] << 16);
            const unsigned pl = (unsigned)(unsigned short)v0l[j] | ((unsigned)(unsigned short)v1l[j] << 16);
            *(unsigned*)&Vth[d][2 * kp] = ph;
            *(unsigned*)&Vtl[d][2 * kp] = pl;
        }

        // K fragments direct from global (pre-scaled by 1/8)
        bf16x8 kfh[4][2], kfl[4][2];
        #pragma unroll
        for (int fb = 0; fb < 4; ++fb) {
            const short* krh = Kh + base + (size_t)(kb + 16 * fb + c) * HD;
            const short* krl = Kl + base + (size_t)(kb + 16 * fb + c) * HD;
            #pragma unroll
            for (int kh = 0; kh < 2; ++kh) {
                kfh[fb][kh] = *(const bf16x8*)(krh + kh * 32 + 8 * g);
                kfl[fb][kh] = *(const bf16x8*)(krl + kh * 32 + 8 * g);
            }
        }

        // S = Q (K/8)^T via bf16x3
        f32x4 sfr[4];
        #pragma unroll
        for (int fb = 0; fb < 4; ++fb) {
            f32x4 s = fz;
            #pragma unroll
            for (int kh = 0; kh < 2; ++kh) {
                s = __builtin_amdgcn_mfma_f32_16x16x32_bf16(qfh[kh], kfh[fb][kh], s, 0, 0, 0);
                s = __builtin_amdgcn_mfma_f32_16x16x32_bf16(qfh[kh], kfl[fb][kh], s, 0, 0, 0);
                s = __builtin_amdgcn_mfma_f32_16x16x32_bf16(qfl[kh], kfh[fb][kh], s, 0, 0, 0);
            }
            sfr[fb] = s;
        }

        // causal mask (diagonal tile only). Query row within the 64-tile is
        // w*16 + 4g + r (wave strip offset w*16 — REQUIRED); key col 16fb+c.
        if (kt == qt) {
            #pragma unroll
            for (int fb = 0; fb < 4; ++fb)
                #pragma unroll
                for (int r = 0; r < 4; ++r) {
                    const int rl = w * 16 + 4 * g + r;
                    const int cl = 16 * fb + c;
                    if (cl > rl) sfr[fb][r] = -1e30f;
                }
        }

        // online softmax (rows live in 16-lane groups)
        #pragma unroll
        for (int r = 0; r < 4; ++r) {
            float mx = fmaxf(fmaxf(sfr[0][r], sfr[1][r]), fmaxf(sfr[2][r], sfr[3][r]));
            mx = fmaxf(mx, __shfl_xor(mx, 1, 16));
            mx = fmaxf(mx, __shfl_xor(mx, 2, 16));
            mx = fmaxf(mx, __shfl_xor(mx, 4, 16));
            mx = fmaxf(mx, __shfl_xor(mx, 8, 16));
            const float mnew  = fmaxf(m_i[r], mx);
            const float alpha = __expf(m_i[r] - mnew);
            float p[4], rs = 0.f;
            #pragma unroll
            for (int fb = 0; fb < 4; ++fb) { p[fb] = __expf(sfr[fb][r] - mnew); rs += p[fb]; }
            rs += __shfl_xor(rs, 1, 16);
            rs += __shfl_xor(rs, 2, 16);
            rs += __shfl_xor(rs, 4, 16);
            rs += __shfl_xor(rs, 8, 16);
            l_i[r] = l_i[r] * alpha + rs;
            m_i[r] = mnew;
            #pragma unroll
            for (int fb = 0; fb < 4; ++fb) {
                o_acc[fb][r] *= alpha;
                Pw[w][4 * g + r][16 * fb + c] = p[fb];
            }
        }

        __syncthreads();   // barrier B: Vt staged + P written

        // P fragments (rows = c) + split
        bf16x8 pfh[2], pfl[2];
        #pragma unroll
        for (int kh = 0; kh < 2; ++kh) {
            float fv[8];
            *(float4*)&fv[0] = *(const float4*)&Pw[w][c][kh * 32 + 8 * g];
            *(float4*)&fv[4] = *(const float4*)&Pw[w][c][kh * 32 + 8 * g + 4];
            split8(fv, pfh[kh], pfl[kh]);
        }

        // O += P V (bf16x3)
        #pragma unroll
        for (int fb = 0; fb < 4; ++fb) {
            #pragma unroll
            for (int kh = 0; kh < 2; ++kh) {
                const bf16x8 vfh = *(const bf16x8*)&Vth[16 * fb + c][kh * 32 + 8 * g];
                const bf16x8 vfl = *(const bf16x8*)&Vtl[16 * fb + c][kh * 32 + 8 * g];
                o_acc[fb] = __builtin_amdgcn_mfma_f32_16x16x32_bf16(pfh[kh], vfh, o_acc[fb], 0, 0, 0);
                o_acc[fb] = __builtin_amdgcn_mfma_f32_16x16x32_bf16(pfh[kh], vfl, o_acc[fb], 0, 0, 0);
                o_acc[fb] = __builtin_amdgcn_mfma_f32_16x16x32_bf16(pfl[kh], vfh, o_acc[fb], 0, 0, 0);
            }
        }
    }

    // epilogue: normalize, split to bf16 hi/lo, write [B][T][C]
    const int b = bh >> 4;
    const int h = bh & 15;
    #pragma unroll
    for (int r = 0; r < 4; ++r) {
        const int t = qt * 64 + w * 16 + 4 * g + r;
        const float inv = 1.0f / l_i[r];
        #pragma unroll
        for (int fb = 0; fb < 4; ++fb) {
            const float val = o_acc[fb][r] * inv;
            short hi, lo;
            split1(val, hi, lo);
            const size_t idx = (size_t)(b * SEQ_T + t) * CDIM + h * HD + 16 * fb + c;
            AOh[idx] = hi;
            AOl[idx] = lo;
        }
    }
}

// ---------------------------------------------------------------------------
extern "C" void kernel_launch(void* const* d_in, const int* in_sizes, int n_in,
                              void* d_out, int out_size, void* d_ws, size_t ws_size,
                              hipStream_t stream) {
    (void)in_sizes; (void)n_in; (void)out_size; (void)ws_size;

    const float* x    = (const float*)d_in[0];
    const float* Wqkv = (const float*)d_in[2];
    const float* bqkv = (const float*)d_in[3];
    const float* Wo   = (const float*)d_in[4];
    const float* bo   = (const float*)d_in[5];
    float* out = (float*)d_out;

    // workspace layout — peak 72.3 MB (QKV-part GEMM phase)
    float* ws   = (float*)d_ws;
    float* cosT = ws;                               // 2048*64 f32
    float* sinT = cosT + SEQ_T * HD;
    const size_t QKV = (size_t)BH * SEQ_T * HD;     // 4.19M elements
    short* Qh = (short*)(sinT + SEQ_T * HD);
    short* Ql  = Qh + QKV;
    short* Kh  = Ql + QKV;
    short* Kl  = Kh + QKV;
    short* Vh  = Kl + QKV;
    short* Vl  = Vh + QKV;
    short* xh  = Vl + QKV;                          // [4096][1024] bf16 hi
    short* xl  = xh + (size_t)MROWS * CDIM;         // lo
    short* Wbh = xl + (size_t)MROWS * CDIM;         // [1024][1024] W-split buf (serially reused)
    short* Wbl = Wbh + (size_t)CDIM * CDIM;
    // attn output aliases xh/xl (dead after the QKV GEMMs)
    short* AOh = xh;
    short* AOl = xl;

    rope_table_kernel<<<SEQ_T, HD, 0, stream>>>(cosT, sinT);

    split_kernel<<<2048, 256, 0, stream>>>(x, xh, xl, MROWS * CDIM / 8);

    const dim3 ggrid(MROWS / 64, CDIM / 128);   // (64, 8) = 512 blocks

    // Q part
    split_kernel<<<512, 256, 0, stream>>>(Wqkv, Wbh, Wbl, CDIM * CDIM / 8);
    gemm_mfma_kernel<0><<<ggrid, 256, 0, stream>>>(
        xh, xl, Wbh, Wbl, bqkv, cosT, sinT, Qh, Ql, nullptr, MROWS, CDIM, CDIM);
    // K part (stream order makes Wbuf reuse safe)
    split_kernel<<<512, 256, 0, stream>>>(Wqkv + (size_t)CDIM * CDIM, Wbh, Wbl, CDIM * CDIM / 8);
    gemm_mfma_kernel<1><<<ggrid, 256, 0, stream>>>(
        xh, xl, Wbh, Wbl, bqkv + CDIM, cosT, sinT, Kh, Kl, nullptr, MROWS, CDIM, CDIM);
    // V part
    split_kernel<<<512, 256, 0, stream>>>(Wqkv + (size_t)2 * CDIM * CDIM, Wbh, Wbl, CDIM * CDIM / 8);
    gemm_mfma_kernel<2><<<ggrid, 256, 0, stream>>>(
        xh, xl, Wbh, Wbl, bqkv + 2 * CDIM, cosT, sinT, Vh, Vl, nullptr, MROWS, CDIM, CDIM);

    // causal flash attention (MFMA)
    attn_mfma_kernel<<<dim3(SEQ_T / 64, BH), 256, 0, stream>>>(
        Qh, Ql, Kh, Kl, Vh, Vl, AOh, AOl);

    // output projection
    split_kernel<<<512, 256, 0, stream>>>(Wo, Wbh, Wbl, CDIM * CDIM / 8);
    gemm_mfma_kernel<3><<<ggrid, 256, 0, stream>>>(
        AOh, AOl, Wbh, Wbl, bo, nullptr, nullptr, nullptr, nullptr, out, MROWS, CDIM, CDIM);
}

// Round 5
// 325.325 us; speedup vs baseline: 3.1136x; 1.7580x over previous
//
#include <hip/hip_runtime.h>
#include <math.h>

// Problem constants: B=2, T=2048, C=1024, H=16, hd=64
#define SEQ_T 2048
#define CDIM 1024
#define HD 64
#define NH 16
#define NB 2
#define BH (NB * NH)          // 32
#define MROWS (NB * SEQ_T)    // 4096

typedef __attribute__((ext_vector_type(8))) short bf16x8;
typedef __attribute__((ext_vector_type(4))) float f32x4;
typedef _Float16 half_t;
typedef __attribute__((ext_vector_type(8))) _Float16 f16x8;
typedef __attribute__((ext_vector_type(4))) _Float16 f16x4;

__device__ inline short f2bf(float f) {
    unsigned u = __float_as_uint(f);
    u += 0x7fff + ((u >> 16) & 1);          // RNE to bf16
    return (short)(u >> 16);
}
__device__ inline float bf2f(short s) {
    return __uint_as_float(((unsigned)(unsigned short)s) << 16);
}
__device__ inline void split1(float f, short& h, short& l) {
    h = f2bf(f);
    l = f2bf(f - bf2f(h));
}
__device__ inline void split8(const float* f, bf16x8& hi, bf16x8& lo) {
    #pragma unroll
    for (int i = 0; i < 8; ++i) {
        short h, l;
        split1(f[i], h, l);
        hi[i] = h; lo[i] = l;
    }
}

// ---------------------------------------------------------------------------
// RoPE tables: cos[t][d] = cos(t * inv_freq[d%32]), inv_freq[i]=10000^(-2i/64)
// ---------------------------------------------------------------------------
__global__ void rope_table_kernel(float* __restrict__ cosT, float* __restrict__ sinT) {
    const int t = blockIdx.x;
    const int d = threadIdx.x;          // 0..63
    const int i = d & 31;
    const float inv = powf(10000.0f, -((float)(2 * i) / 64.0f));
    const float f = (float)t * inv;
    cosT[t * HD + d] = cosf(f);
    sinT[t * HD + d] = sinf(f);
}

// ---------------------------------------------------------------------------
// fp32 -> bf16 hi/lo pre-split (memory-bound)
// ---------------------------------------------------------------------------
__global__ __launch_bounds__(256) void split_kernel(
    const float* __restrict__ in, short* __restrict__ hi, short* __restrict__ lo, int n8)
{
    for (int i = blockIdx.x * blockDim.x + threadIdx.x; i < n8; i += gridDim.x * blockDim.x) {
        float fv[8];
        *(float4*)&fv[0] = *(const float4*)(in + (size_t)i * 8);
        *(float4*)&fv[4] = *(const float4*)(in + (size_t)i * 8 + 4);
        bf16x8 h, l;
        split8(fv, h, l);
        ((bf16x8*)hi)[i] = h;
        ((bf16x8*)lo)[i] = l;
    }
}

// ---------------------------------------------------------------------------
// bf16x3 MFMA GEMM (proven config): Y[m][n] = sum_k A[m][k]*W[n][k] + bias[n]
// 64x128 tile, BK=32, 4 waves (2x2), wave = 32x64. A/B frags share the k-map
// (k=8g+i) so hw k-permutation cancels. C/D (m89): col=lane&15, row=4g+reg.
// PART 0/1/2 (Q/K/V): bias + RoPE for Q/K (partner via shfl_xor 1), K scaled
//   by 0.125, writes SINGLE fp16 at [B*H][T][hd]  (attn consumes fp16 now).
// PART 3: writes fp32 Y + bias (out projection).
// ---------------------------------------------------------------------------
template <int PART>
__global__ __launch_bounds__(256) void gemm_mfma_kernel(
    const short* __restrict__ Ahg, const short* __restrict__ Alg,   // [M][K]
    const short* __restrict__ Bhg, const short* __restrict__ Blg,   // [N][K]
    const float* __restrict__ bias,
    const float* __restrict__ cosT, const float* __restrict__ sinT,
    half_t* __restrict__ PQ,      // PART 0..2 target (fp16)
    float* __restrict__ Yo,       // PART 3 target
    int M, int N, int K)
{
    __shared__ short As_h[64][40],  As_l[64][40];    // [m][k], pad 40
    __shared__ short Bs_h[128][40], Bs_l[128][40];   // [n][k]

    const int tid  = threadIdx.x;
    const int row0 = blockIdx.x * 64;
    const int col0 = blockIdx.y * 128;
    const int lane = tid & 63;
    const int w    = tid >> 6;
    const int wr   = (w >> 1) * 32;
    const int wc   = (w & 1) * 64;
    const int g    = lane >> 4;
    const int c    = lane & 15;

    const int r0   = tid >> 2;          // 0..63
    const int col8 = (tid & 3) * 8;     // 0,8,16,24

    const short* pAh = Ahg + (size_t)(row0 + r0) * K + col8;
    const short* pAl = Alg + (size_t)(row0 + r0) * K + col8;
    const short* pBh0 = Bhg + (size_t)(col0 + r0) * K + col8;
    const short* pBh1 = pBh0 + (size_t)64 * K;
    const short* pBl0 = Blg + (size_t)(col0 + r0) * K + col8;
    const short* pBl1 = pBl0 + (size_t)64 * K;

    const f32x4 fz = {0.f, 0.f, 0.f, 0.f};
    f32x4 acc[2][4];
    #pragma unroll
    for (int i = 0; i < 2; ++i)
        #pragma unroll
        for (int j = 0; j < 4; ++j)
            acc[i][j] = fz;

    bf16x8 sa_h, sa_l, sb_h0, sb_h1, sb_l0, sb_l1;
    sa_h  = *(const bf16x8*)(pAh);
    sa_l  = *(const bf16x8*)(pAl);
    sb_h0 = *(const bf16x8*)(pBh0);
    sb_h1 = *(const bf16x8*)(pBh1);
    sb_l0 = *(const bf16x8*)(pBl0);
    sb_l1 = *(const bf16x8*)(pBl1);

    for (int k0 = 0; k0 < K; k0 += 32) {
        __syncthreads();
        *(bf16x8*)&As_h[r0][col8]      = sa_h;
        *(bf16x8*)&As_l[r0][col8]      = sa_l;
        *(bf16x8*)&Bs_h[r0][col8]      = sb_h0;
        *(bf16x8*)&Bs_h[r0 + 64][col8] = sb_h1;
        *(bf16x8*)&Bs_l[r0][col8]      = sb_l0;
        *(bf16x8*)&Bs_l[r0 + 64][col8] = sb_l1;
        if (k0 + 32 < K) {
            const int kn = k0 + 32;
            sa_h  = *(const bf16x8*)(pAh + kn);
            sa_l  = *(const bf16x8*)(pAl + kn);
            sb_h0 = *(const bf16x8*)(pBh0 + kn);
            sb_h1 = *(const bf16x8*)(pBh1 + kn);
            sb_l0 = *(const bf16x8*)(pBl0 + kn);
            sb_l1 = *(const bf16x8*)(pBl1 + kn);
        }
        __syncthreads();

        bf16x8 afh[2], afl[2], bfh[4], bfl[4];
        #pragma unroll
        for (int am = 0; am < 2; ++am) {
            afh[am] = *(const bf16x8*)&As_h[wr + 16 * am + c][8 * g];
            afl[am] = *(const bf16x8*)&As_l[wr + 16 * am + c][8 * g];
        }
        #pragma unroll
        for (int bn = 0; bn < 4; ++bn) {
            bfh[bn] = *(const bf16x8*)&Bs_h[wc + 16 * bn + c][8 * g];
            bfl[bn] = *(const bf16x8*)&Bs_l[wc + 16 * bn + c][8 * g];
        }
        #pragma unroll
        for (int am = 0; am < 2; ++am)
            #pragma unroll
            for (int bn = 0; bn < 4; ++bn) {
                acc[am][bn] = __builtin_amdgcn_mfma_f32_16x16x32_bf16(afh[am], bfh[bn], acc[am][bn], 0, 0, 0);
                acc[am][bn] = __builtin_amdgcn_mfma_f32_16x16x32_bf16(afl[am], bfh[bn], acc[am][bn], 0, 0, 0);
                acc[am][bn] = __builtin_amdgcn_mfma_f32_16x16x32_bf16(afh[am], bfl[bn], acc[am][bn], 0, 0, 0);
            }
    }

    if (PART < 3) {
        #pragma unroll
        for (int am = 0; am < 2; ++am) {
            #pragma unroll
            for (int bn = 0; bn < 4; ++bn) {
                const int n = col0 + wc + 16 * bn + c;   // 0..1023
                const int h = n >> 6;
                const int d = n & 63;
                const float bsv = bias[n];
                #pragma unroll
                for (int r = 0; r < 4; ++r) {
                    const int m = row0 + wr + 16 * am + 4 * g + r;
                    const int b = m >> 11;
                    const int t = m & (SEQ_T - 1);
                    const float v  = acc[am][bn][r] + bsv;
                    const float vp = __shfl_xor(v, 1, 16);   // partner col n^1, same row
                    float rv;
                    if (PART == 2) {
                        rv = v;
                    } else {
                        const float cs = cosT[t * HD + d], sn = sinT[t * HD + d];
                        rv = (d & 1) ? (v * cs + vp * sn) : (v * cs - vp * sn);
                    }
                    if (PART == 1) rv *= 0.125f;   // fold 1/sqrt(hd) into K
                    PQ[(((size_t)(b * NH + h) * SEQ_T) + t) * HD + d] = (half_t)rv;
                }
            }
        }
    } else {
        #pragma unroll
        for (int am = 0; am < 2; ++am)
            #pragma unroll
            for (int bn = 0; bn < 4; ++bn) {
                const int n = col0 + wc + 16 * bn + c;
                const float bsv = bias[n];
                #pragma unroll
                for (int r = 0; r < 4; ++r) {
                    const int m = row0 + wr + 16 * am + 4 * g + r;
                    Yo[(size_t)m * N + n] = acc[am][bn][r] + bsv;
                }
            }
    }
}

// ---------------------------------------------------------------------------
// MFMA flash attention, fp16 operands, fp32 accum/softmax.
// Grid (bh=32, 16) — blockIdx.x = bh so id%8 = bh%8 pins each bh to one XCD.
// Block 512 = 8 waves; Q-tile 128 rows (wave w owns rows qt2*128+w*16..+15).
// K staged row-major in LDS, V staged transposed ([d][key]) via paired-u32
// writes; both loaded once per block, shared by 8 waves; next tile
// reg-prefetched under compute. P goes through per-wave fp16 LDS strip
// (same-wave W->R ordered via lgkmcnt(0)). Causal: per-wave tile skip +
// element mask on boundary tiles. qt2 = 15 - blockIdx.y: heavy blocks first.
// ---------------------------------------------------------------------------
__global__ __launch_bounds__(512, 4) void attn_mfma_kernel(
    const half_t* __restrict__ Qf, const half_t* __restrict__ Kf,
    const half_t* __restrict__ Vf,
    short* __restrict__ AOh, short* __restrict__ AOl)
{
    __shared__ half_t Ks[64][72];       // [key][d]   row stride 144B (16B-mult)
    __shared__ half_t Vt[64][72];       // [d][key]
    __shared__ half_t Pf[8][16][72];    // per-wave P strip [row][key]

    const int bh  = blockIdx.x;
    const int qt2 = 15 - blockIdx.y;    // heavy blocks first
    const int tid = threadIdx.x;
    const int w    = tid >> 6;
    const int lane = tid & 63;
    const int g    = lane >> 4;         // k-group: holds k = 8g..8g+7 (+32kh)
    const int c    = lane & 15;

    const int R0 = qt2 * 128 + w * 16;  // strip's first (global) row
    const size_t base = (size_t)bh * SEQ_T * HD;

    // Q fragments (rows R0 + c)
    f16x8 qf[2];
    {
        const half_t* qrow = Qf + base + (size_t)(R0 + c) * HD;
        qf[0] = *(const f16x8*)(qrow + 8 * g);
        qf[1] = *(const f16x8*)(qrow + 32 + 8 * g);
    }

    const f32x4 fz = {0.f, 0.f, 0.f, 0.f};
    f32x4 o_acc[4];
    float m_i[4], l_i[4];
    #pragma unroll
    for (int r = 0; r < 4; ++r) { o_acc[r] = fz; m_i[r] = -1e30f; l_i[r] = 0.f; }

    // staging maps
    const int kr  = tid >> 3;           // K row 0..63
    const int kc8 = (tid & 7) * 8;      // K col chunk
    const int kp  = tid & 31;           // V key pair
    const int d0  = (tid >> 5) * 4;     // V d chunk 0..60

    const int nt = 2 * qt2 + 2;

    // prologue: stage regs for kt = 0
    f16x8 sk = *(const f16x8*)(Kf + base + (size_t)kr * HD + kc8);
    f16x4 sv0 = *(const f16x4*)(Vf + base + (size_t)(2 * kp) * HD + d0);
    f16x4 sv1 = *(const f16x4*)(Vf + base + (size_t)(2 * kp + 1) * HD + d0);

    for (int kt = 0; kt < nt; ++kt) {
        __syncthreads();   // A: prior iteration's LDS reads complete
        *(f16x8*)&Ks[kr][kc8] = sk;
        #pragma unroll
        for (int j = 0; j < 4; ++j) {
            union { half_t h[2]; unsigned u; } pk;
            pk.h[0] = sv0[j]; pk.h[1] = sv1[j];
            *(unsigned*)&Vt[d0 + j][2 * kp] = pk.u;
        }
        if (kt + 1 < nt) {   // prefetch next tile (latency hidden under compute)
            const int kb1 = (kt + 1) * 64;
            sk  = *(const f16x8*)(Kf + base + (size_t)(kb1 + kr) * HD + kc8);
            sv0 = *(const f16x4*)(Vf + base + (size_t)(kb1 + 2 * kp) * HD + d0);
            sv1 = *(const f16x4*)(Vf + base + (size_t)(kb1 + 2 * kp + 1) * HD + d0);
        }
        __syncthreads();   // B: staging visible

        const int kb = kt * 64;
        if (kb <= R0 + 15) {   // wave-uniform: tile not fully masked for strip
            // ---- S = Q (K/8)^T ----
            f32x4 sfr[4];
            #pragma unroll
            for (int fb = 0; fb < 4; ++fb) {
                f32x4 s = fz;
                #pragma unroll
                for (int kh = 0; kh < 2; ++kh) {
                    const f16x8 kfr = *(const f16x8*)&Ks[16 * fb + c][32 * kh + 8 * g];
                    s = __builtin_amdgcn_mfma_f32_16x16x32_f16(qf[kh], kfr, s, 0, 0, 0);
                }
                sfr[fb] = s;
            }

            // ---- causal mask (boundary tiles only) ----
            if (kb + 63 > R0) {
                #pragma unroll
                for (int fb = 0; fb < 4; ++fb)
                    #pragma unroll
                    for (int r = 0; r < 4; ++r) {
                        const int rg = R0 + 4 * g + r;
                        const int cg = kb + 16 * fb + c;
                        if (cg > rg) sfr[fb][r] = -1e30f;
                    }
            }

            // ---- online softmax (rows live in 16-lane groups) ----
            #pragma unroll
            for (int r = 0; r < 4; ++r) {
                float mx = fmaxf(fmaxf(sfr[0][r], sfr[1][r]), fmaxf(sfr[2][r], sfr[3][r]));
                mx = fmaxf(mx, __shfl_xor(mx, 1, 16));
                mx = fmaxf(mx, __shfl_xor(mx, 2, 16));
                mx = fmaxf(mx, __shfl_xor(mx, 4, 16));
                mx = fmaxf(mx, __shfl_xor(mx, 8, 16));
                const float mnew  = fmaxf(m_i[r], mx);
                const float alpha = __expf(m_i[r] - mnew);
                float p[4], rs = 0.f;
                #pragma unroll
                for (int fb = 0; fb < 4; ++fb) { p[fb] = __expf(sfr[fb][r] - mnew); rs += p[fb]; }
                rs += __shfl_xor(rs, 1, 16);
                rs += __shfl_xor(rs, 2, 16);
                rs += __shfl_xor(rs, 4, 16);
                rs += __shfl_xor(rs, 8, 16);
                l_i[r] = l_i[r] * alpha + rs;
                m_i[r] = mnew;
                #pragma unroll
                for (int fb = 0; fb < 4; ++fb) {
                    o_acc[fb][r] *= alpha;
                    Pf[w][4 * g + r][16 * fb + c] = (half_t)p[fb];   // C/D -> [row][key]
                }
            }

            // same-wave LDS W->R: ensure P writes retired before transposed reads
            asm volatile("s_waitcnt lgkmcnt(0)" ::: "memory");

            // ---- O += P V ----
            f16x8 pf[2];
            pf[0] = *(const f16x8*)&Pf[w][c][8 * g];
            pf[1] = *(const f16x8*)&Pf[w][c][32 + 8 * g];
            #pragma unroll
            for (int fb = 0; fb < 4; ++fb) {
                #pragma unroll
                for (int kh = 0; kh < 2; ++kh) {
                    const f16x8 vfr = *(const f16x8*)&Vt[16 * fb + c][32 * kh + 8 * g];
                    o_acc[fb] = __builtin_amdgcn_mfma_f32_16x16x32_f16(pf[kh], vfr, o_acc[fb], 0, 0, 0);
                }
            }
        }
    }

    // ---- epilogue: normalize, split to bf16 hi/lo, write [B][T][C] ----
    const int b = bh >> 4;
    const int h = bh & 15;
    #pragma unroll
    for (int r = 0; r < 4; ++r) {
        const int t = qt2 * 128 + w * 16 + 4 * g + r;
        const float inv = 1.0f / l_i[r];
        #pragma unroll
        for (int fb = 0; fb < 4; ++fb) {
            const float val = o_acc[fb][r] * inv;
            short hi, lo;
            split1(val, hi, lo);
            const size_t idx = (size_t)(b * SEQ_T + t) * CDIM + h * HD + 16 * fb + c;
            AOh[idx] = hi;
            AOl[idx] = lo;
        }
    }
}

// ---------------------------------------------------------------------------
extern "C" void kernel_launch(void* const* d_in, const int* in_sizes, int n_in,
                              void* d_out, int out_size, void* d_ws, size_t ws_size,
                              hipStream_t stream) {
    (void)in_sizes; (void)n_in; (void)out_size; (void)ws_size;

    const float* x    = (const float*)d_in[0];
    const float* Wqkv = (const float*)d_in[2];
    const float* bqkv = (const float*)d_in[3];
    const float* Wo   = (const float*)d_in[4];
    const float* bo   = (const float*)d_in[5];
    float* out = (float*)d_out;

    // workspace layout — peak ~47 MB
    float* ws   = (float*)d_ws;
    float* cosT = ws;                               // 2048*64 f32
    float* sinT = cosT + SEQ_T * HD;
    const size_t QKV = (size_t)BH * SEQ_T * HD;     // 4.19M elements
    half_t* Qf = (half_t*)(sinT + SEQ_T * HD);      // fp16 Q/K/V
    half_t* Kf = Qf + QKV;
    half_t* Vf = Kf + QKV;
    short* xh  = (short*)(Vf + QKV);                // [4096][1024] bf16 hi
    short* xl  = xh + (size_t)MROWS * CDIM;         // lo
    short* Wbh = xl + (size_t)MROWS * CDIM;         // [1024][1024] W-split buf (serially reused)
    short* Wbl = Wbh + (size_t)CDIM * CDIM;
    // attn output aliases xh/xl (dead after the QKV GEMMs)
    short* AOh = xh;
    short* AOl = xl;

    rope_table_kernel<<<SEQ_T, HD, 0, stream>>>(cosT, sinT);

    split_kernel<<<2048, 256, 0, stream>>>(x, xh, xl, MROWS * CDIM / 8);

    const dim3 ggrid(MROWS / 64, CDIM / 128);   // (64, 8) = 512 blocks

    // Q part
    split_kernel<<<512, 256, 0, stream>>>(Wqkv, Wbh, Wbl, CDIM * CDIM / 8);
    gemm_mfma_kernel<0><<<ggrid, 256, 0, stream>>>(
        xh, xl, Wbh, Wbl, bqkv, cosT, sinT, Qf, nullptr, MROWS, CDIM, CDIM);
    // K part (stream order makes Wbuf reuse safe)
    split_kernel<<<512, 256, 0, stream>>>(Wqkv + (size_t)CDIM * CDIM, Wbh, Wbl, CDIM * CDIM / 8);
    gemm_mfma_kernel<1><<<ggrid, 256, 0, stream>>>(
        xh, xl, Wbh, Wbl, bqkv + CDIM, cosT, sinT, Kf, nullptr, MROWS, CDIM, CDIM);
    // V part
    split_kernel<<<512, 256, 0, stream>>>(Wqkv + (size_t)2 * CDIM * CDIM, Wbh, Wbl, CDIM * CDIM / 8);
    gemm_mfma_kernel<2><<<ggrid, 256, 0, stream>>>(
        xh, xl, Wbh, Wbl, bqkv + 2 * CDIM, cosT, sinT, Vf, nullptr, MROWS, CDIM, CDIM);

    // causal flash attention (fp16 MFMA), bh-major grid for XCD L2 locality
    attn_mfma_kernel<<<dim3(BH, SEQ_T / 128), 512, 0, stream>>>(
        Qf, Kf, Vf, AOh, AOl);

    // output projection (bf16x3)
    split_kernel<<<512, 256, 0, stream>>>(Wo, Wbh, Wbl, CDIM * CDIM / 8);
    gemm_mfma_kernel<3><<<ggrid, 256, 0, stream>>>(
        AOh, AOl, Wbh, Wbl, bo, nullptr, nullptr, nullptr, out, MROWS, CDIM, CDIM);
}

// Round 6
// 251.315 us; speedup vs baseline: 4.0305x; 1.2945x over previous
//
#include <hip/hip_runtime.h>
#include <math.h>

// Problem constants: B=2, T=2048, C=1024, H=16, hd=64
#define SEQ_T 2048
#define CDIM 1024
#define HD 64
#define NH 16
#define NB 2
#define BH (NB * NH)          // 32
#define MROWS (NB * SEQ_T)    // 4096

typedef __attribute__((ext_vector_type(8))) short bf16x8;
typedef __attribute__((ext_vector_type(4))) float f32x4;
typedef _Float16 half_t;
typedef __attribute__((ext_vector_type(8))) _Float16 f16x8;
typedef __attribute__((ext_vector_type(4))) _Float16 f16x4;

__device__ inline short f2bf(float f) {
    unsigned u = __float_as_uint(f);
    u += 0x7fff + ((u >> 16) & 1);          // RNE to bf16
    return (short)(u >> 16);
}
__device__ inline float bf2f(short s) {
    return __uint_as_float(((unsigned)(unsigned short)s) << 16);
}
__device__ inline void split1(float f, short& h, short& l) {
    h = f2bf(f);
    l = f2bf(f - bf2f(h));
}
__device__ inline void split8(const float* f, bf16x8& hi, bf16x8& lo) {
    #pragma unroll
    for (int i = 0; i < 8; ++i) {
        short h, l;
        split1(f[i], h, l);
        hi[i] = h; lo[i] = l;
    }
}

// ---------------------------------------------------------------------------
// RoPE tables: cos[t][d] = cos(t * inv_freq[d%32]), inv_freq[i]=10000^(-2i/64)
// ---------------------------------------------------------------------------
__global__ void rope_table_kernel(float* __restrict__ cosT, float* __restrict__ sinT) {
    const int t = blockIdx.x;
    const int d = threadIdx.x;          // 0..63
    const int i = d & 31;
    const float inv = powf(10000.0f, -((float)(2 * i) / 64.0f));
    const float f = (float)t * inv;
    cosT[t * HD + d] = cosf(f);
    sinT[t * HD + d] = sinf(f);
}

// ---------------------------------------------------------------------------
// fp32 -> fp16 convert (RNE), vectorized
// ---------------------------------------------------------------------------
__global__ __launch_bounds__(256) void conv_half_kernel(
    const float* __restrict__ in, half_t* __restrict__ out, int n8)
{
    for (int i = blockIdx.x * blockDim.x + threadIdx.x; i < n8; i += gridDim.x * blockDim.x) {
        const float4 a = *(const float4*)(in + (size_t)i * 8);
        const float4 b = *(const float4*)(in + (size_t)i * 8 + 4);
        f16x8 o;
        o[0] = (half_t)a.x; o[1] = (half_t)a.y; o[2] = (half_t)a.z; o[3] = (half_t)a.w;
        o[4] = (half_t)b.x; o[5] = (half_t)b.y; o[6] = (half_t)b.z; o[7] = (half_t)b.w;
        *(f16x8*)(out + (size_t)i * 8) = o;
    }
}

// ---------------------------------------------------------------------------
// fp32 -> bf16 hi/lo pre-split (for the bf16x3 out-projection weight)
// ---------------------------------------------------------------------------
__global__ __launch_bounds__(256) void split_kernel(
    const float* __restrict__ in, short* __restrict__ hi, short* __restrict__ lo, int n8)
{
    for (int i = blockIdx.x * blockDim.x + threadIdx.x; i < n8; i += gridDim.x * blockDim.x) {
        float fv[8];
        *(float4*)&fv[0] = *(const float4*)(in + (size_t)i * 8);
        *(float4*)&fv[4] = *(const float4*)(in + (size_t)i * 8 + 4);
        bf16x8 h, l;
        split8(fv, h, l);
        ((bf16x8*)hi)[i] = h;
        ((bf16x8*)lo)[i] = l;
    }
}

// ---------------------------------------------------------------------------
// fp16 MFMA QKV GEMM: qkv[m][n] = sum_k x[m][k]*Wqkv[n][k] + bias[n], N=3072.
// 128x128 tile, BK=32, 4 waves (2x2), wave = 64x64 (4x4 frags of 16x16x32).
// A/B frags share the k-map (k=8g+i) so hw k-permutation cancels.
// C/D (m89): col=lane&15, row=4*(lane>>4)+reg.
// Epilogue: bias, decode n -> (mat,h,d), RoPE Q/K (partner via shfl_xor 1),
// K scaled 0.125, writes fp16 to Q/K/V at [B*H][T][hd].
// ---------------------------------------------------------------------------
__global__ __launch_bounds__(256) void qkv_gemm_fp16_kernel(
    const half_t* __restrict__ Ag,    // [M][K] fp16 x
    const half_t* __restrict__ Bg,    // [N][K] fp16 Wqkv
    const float* __restrict__ bias,
    const float* __restrict__ cosT, const float* __restrict__ sinT,
    half_t* __restrict__ Qf, half_t* __restrict__ Kf, half_t* __restrict__ Vf,
    int M, int N, int K)
{
    __shared__ half_t As[128][40];   // [m][k], stride 80B (16B-mult); frag reads 2-way banks (free)
    __shared__ half_t Bs[128][40];   // [n][k]

    const int tid  = threadIdx.x;
    const int row0 = blockIdx.x * 128;
    const int col0 = blockIdx.y * 128;
    const int lane = tid & 63;
    const int w    = tid >> 6;
    const int wr   = (w >> 1) * 64;
    const int wc   = (w & 1) * 64;
    const int g    = lane >> 4;         // k-group: holds k = 8g..8g+7 (+16 for hi half)
    const int c    = lane & 15;

    // staging: chunk = tid covers row tid>>2, chunk tid+256 covers row 64+(tid>>2)
    const int r0   = tid >> 2;          // 0..63
    const int col8 = (tid & 3) * 8;     // 0,8,16,24

    const half_t* pA0 = Ag + (size_t)(row0 + r0) * K + col8;
    const half_t* pA1 = pA0 + (size_t)64 * K;
    const half_t* pB0 = Bg + (size_t)(col0 + r0) * K + col8;
    const half_t* pB1 = pB0 + (size_t)64 * K;

    const f32x4 fz = {0.f, 0.f, 0.f, 0.f};
    f32x4 acc[4][4];
    #pragma unroll
    for (int i = 0; i < 4; ++i)
        #pragma unroll
        for (int j = 0; j < 4; ++j)
            acc[i][j] = fz;

    // prologue: k0=0 staging regs
    f16x8 sa0 = *(const f16x8*)(pA0);
    f16x8 sa1 = *(const f16x8*)(pA1);
    f16x8 sb0 = *(const f16x8*)(pB0);
    f16x8 sb1 = *(const f16x8*)(pB1);

    for (int k0 = 0; k0 < K; k0 += 32) {
        __syncthreads();   // previous iteration's frag reads complete
        *(f16x8*)&As[r0][col8]      = sa0;
        *(f16x8*)&As[r0 + 64][col8] = sa1;
        *(f16x8*)&Bs[r0][col8]      = sb0;
        *(f16x8*)&Bs[r0 + 64][col8] = sb1;
        if (k0 + 32 < K) {   // prefetch next K-slab under MFMA
            const int kn = k0 + 32;
            sa0 = *(const f16x8*)(pA0 + kn);
            sa1 = *(const f16x8*)(pA1 + kn);
            sb0 = *(const f16x8*)(pB0 + kn);
            sb1 = *(const f16x8*)(pB1 + kn);
        }
        __syncthreads();

        f16x8 af[4], bf[4];
        #pragma unroll
        for (int am = 0; am < 4; ++am)
            af[am] = *(const f16x8*)&As[wr + 16 * am + c][8 * g];
        #pragma unroll
        for (int bn = 0; bn < 4; ++bn)
            bf[bn] = *(const f16x8*)&Bs[wc + 16 * bn + c][8 * g];
        #pragma unroll
        for (int am = 0; am < 4; ++am)
            #pragma unroll
            for (int bn = 0; bn < 4; ++bn)
                acc[am][bn] = __builtin_amdgcn_mfma_f32_16x16x32_f16(af[am], bf[bn], acc[am][bn], 0, 0, 0);
    }

    // epilogue: bias + RoPE + scatter to fp16 Q/K/V
    #pragma unroll
    for (int am = 0; am < 4; ++am) {
        #pragma unroll
        for (int bn = 0; bn < 4; ++bn) {
            const int n   = col0 + wc + 16 * bn + c;   // 0..3071
            const int mat = n >> 10;                   // 0=Q 1=K 2=V (uniform per 16-group)
            const int h   = (n >> 6) & 15;
            const int d   = n & 63;
            const float bsv = bias[n];
            half_t* dst = (mat == 0) ? Qf : ((mat == 1) ? Kf : Vf);
            #pragma unroll
            for (int r = 0; r < 4; ++r) {
                const int m = row0 + wr + 16 * am + 4 * g + r;
                const int b = m >> 11;
                const int t = m & (SEQ_T - 1);
                const float v  = acc[am][bn][r] + bsv;
                const float vp = __shfl_xor(v, 1, 16);   // partner col n^1, same row
                float rv;
                if (mat == 2) {
                    rv = v;
                } else {
                    const float cs = cosT[t * HD + d], sn = sinT[t * HD + d];
                    rv = (d & 1) ? (v * cs + vp * sn) : (v * cs - vp * sn);
                    if (mat == 1) rv *= 0.125f;   // fold 1/sqrt(hd) into K
                }
                dst[(((size_t)(b * NH + h) * SEQ_T) + t) * HD + d] = (half_t)rv;
            }
        }
    }
}

// ---------------------------------------------------------------------------
// bf16x3 MFMA out-projection (validated config, unchanged):
// Y[m][n] = sum_k A[m][k]*W[n][k] + bias[n]; 64x128 tile, BK=32, 4 waves.
// ---------------------------------------------------------------------------
__global__ __launch_bounds__(256) void outproj_gemm_kernel(
    const short* __restrict__ Ahg, const short* __restrict__ Alg,   // [M][K]
    const short* __restrict__ Bhg, const short* __restrict__ Blg,   // [N][K]
    const float* __restrict__ bias,
    float* __restrict__ Yo,
    int M, int N, int K)
{
    __shared__ short As_h[64][40],  As_l[64][40];    // [m][k], pad 40
    __shared__ short Bs_h[128][40], Bs_l[128][40];   // [n][k]

    const int tid  = threadIdx.x;
    const int row0 = blockIdx.x * 64;
    const int col0 = blockIdx.y * 128;
    const int lane = tid & 63;
    const int w    = tid >> 6;
    const int wr   = (w >> 1) * 32;
    const int wc   = (w & 1) * 64;
    const int g    = lane >> 4;
    const int c    = lane & 15;

    const int r0   = tid >> 2;          // 0..63
    const int col8 = (tid & 3) * 8;     // 0,8,16,24

    const short* pAh = Ahg + (size_t)(row0 + r0) * K + col8;
    const short* pAl = Alg + (size_t)(row0 + r0) * K + col8;
    const short* pBh0 = Bhg + (size_t)(col0 + r0) * K + col8;
    const short* pBh1 = pBh0 + (size_t)64 * K;
    const short* pBl0 = Blg + (size_t)(col0 + r0) * K + col8;
    const short* pBl1 = pBl0 + (size_t)64 * K;

    const f32x4 fz = {0.f, 0.f, 0.f, 0.f};
    f32x4 acc[2][4];
    #pragma unroll
    for (int i = 0; i < 2; ++i)
        #pragma unroll
        for (int j = 0; j < 4; ++j)
            acc[i][j] = fz;

    bf16x8 sa_h, sa_l, sb_h0, sb_h1, sb_l0, sb_l1;
    sa_h  = *(const bf16x8*)(pAh);
    sa_l  = *(const bf16x8*)(pAl);
    sb_h0 = *(const bf16x8*)(pBh0);
    sb_h1 = *(const bf16x8*)(pBh1);
    sb_l0 = *(const bf16x8*)(pBl0);
    sb_l1 = *(const bf16x8*)(pBl1);

    for (int k0 = 0; k0 < K; k0 += 32) {
        __syncthreads();
        *(bf16x8*)&As_h[r0][col8]      = sa_h;
        *(bf16x8*)&As_l[r0][col8]      = sa_l;
        *(bf16x8*)&Bs_h[r0][col8]      = sb_h0;
        *(bf16x8*)&Bs_h[r0 + 64][col8] = sb_h1;
        *(bf16x8*)&Bs_l[r0][col8]      = sb_l0;
        *(bf16x8*)&Bs_l[r0 + 64][col8] = sb_l1;
        if (k0 + 32 < K) {
            const int kn = k0 + 32;
            sa_h  = *(const bf16x8*)(pAh + kn);
            sa_l  = *(const bf16x8*)(pAl + kn);
            sb_h0 = *(const bf16x8*)(pBh0 + kn);
            sb_h1 = *(const bf16x8*)(pBh1 + kn);
            sb_l0 = *(const bf16x8*)(pBl0 + kn);
            sb_l1 = *(const bf16x8*)(pBl1 + kn);
        }
        __syncthreads();

        bf16x8 afh[2], afl[2], bfh[4], bfl[4];
        #pragma unroll
        for (int am = 0; am < 2; ++am) {
            afh[am] = *(const bf16x8*)&As_h[wr + 16 * am + c][8 * g];
            afl[am] = *(const bf16x8*)&As_l[wr + 16 * am + c][8 * g];
        }
        #pragma unroll
        for (int bn = 0; bn < 4; ++bn) {
            bfh[bn] = *(const bf16x8*)&Bs_h[wc + 16 * bn + c][8 * g];
            bfl[bn] = *(const bf16x8*)&Bs_l[wc + 16 * bn + c][8 * g];
        }
        #pragma unroll
        for (int am = 0; am < 2; ++am)
            #pragma unroll
            for (int bn = 0; bn < 4; ++bn) {
                acc[am][bn] = __builtin_amdgcn_mfma_f32_16x16x32_bf16(afh[am], bfh[bn], acc[am][bn], 0, 0, 0);
                acc[am][bn] = __builtin_amdgcn_mfma_f32_16x16x32_bf16(afl[am], bfh[bn], acc[am][bn], 0, 0, 0);
                acc[am][bn] = __builtin_amdgcn_mfma_f32_16x16x32_bf16(afh[am], bfl[bn], acc[am][bn], 0, 0, 0);
            }
    }

    #pragma unroll
    for (int am = 0; am < 2; ++am)
        #pragma unroll
        for (int bn = 0; bn < 4; ++bn) {
            const int n = col0 + wc + 16 * bn + c;
            const float bsv = bias[n];
            #pragma unroll
            for (int r = 0; r < 4; ++r) {
                const int m = row0 + wr + 16 * am + 4 * g + r;
                Yo[(size_t)m * N + n] = acc[am][bn][r] + bsv;
            }
        }
}

// ---------------------------------------------------------------------------
// MFMA flash attention, fp16 operands, fp32 accum/softmax. (validated r5)
// Grid (bh=32, 16); block 512 = 8 waves; Q-tile 128 rows.
// ---------------------------------------------------------------------------
__global__ __launch_bounds__(512, 4) void attn_mfma_kernel(
    const half_t* __restrict__ Qf, const half_t* __restrict__ Kf,
    const half_t* __restrict__ Vf,
    short* __restrict__ AOh, short* __restrict__ AOl)
{
    __shared__ half_t Ks[64][72];       // [key][d]
    __shared__ half_t Vt[64][72];       // [d][key]
    __shared__ half_t Pf[8][16][72];    // per-wave P strip [row][key]

    const int bh  = blockIdx.x;
    const int qt2 = 15 - blockIdx.y;    // heavy blocks first
    const int tid = threadIdx.x;
    const int w    = tid >> 6;
    const int lane = tid & 63;
    const int g    = lane >> 4;
    const int c    = lane & 15;

    const int R0 = qt2 * 128 + w * 16;
    const size_t base = (size_t)bh * SEQ_T * HD;

    f16x8 qf[2];
    {
        const half_t* qrow = Qf + base + (size_t)(R0 + c) * HD;
        qf[0] = *(const f16x8*)(qrow + 8 * g);
        qf[1] = *(const f16x8*)(qrow + 32 + 8 * g);
    }

    const f32x4 fz = {0.f, 0.f, 0.f, 0.f};
    f32x4 o_acc[4];
    float m_i[4], l_i[4];
    #pragma unroll
    for (int r = 0; r < 4; ++r) { o_acc[r] = fz; m_i[r] = -1e30f; l_i[r] = 0.f; }

    const int kr  = tid >> 3;           // K row 0..63
    const int kc8 = (tid & 7) * 8;      // K col chunk
    const int kp  = tid & 31;           // V key pair
    const int d0  = (tid >> 5) * 4;     // V d chunk

    const int nt = 2 * qt2 + 2;

    f16x8 sk = *(const f16x8*)(Kf + base + (size_t)kr * HD + kc8);
    f16x4 sv0 = *(const f16x4*)(Vf + base + (size_t)(2 * kp) * HD + d0);
    f16x4 sv1 = *(const f16x4*)(Vf + base + (size_t)(2 * kp + 1) * HD + d0);

    for (int kt = 0; kt < nt; ++kt) {
        __syncthreads();
        *(f16x8*)&Ks[kr][kc8] = sk;
        #pragma unroll
        for (int j = 0; j < 4; ++j) {
            union { half_t h[2]; unsigned u; } pk;
            pk.h[0] = sv0[j]; pk.h[1] = sv1[j];
            *(unsigned*)&Vt[d0 + j][2 * kp] = pk.u;
        }
        if (kt + 1 < nt) {
            const int kb1 = (kt + 1) * 64;
            sk  = *(const f16x8*)(Kf + base + (size_t)(kb1 + kr) * HD + kc8);
            sv0 = *(const f16x4*)(Vf + base + (size_t)(kb1 + 2 * kp) * HD + d0);
            sv1 = *(const f16x4*)(Vf + base + (size_t)(kb1 + 2 * kp + 1) * HD + d0);
        }
        __syncthreads();

        const int kb = kt * 64;
        if (kb <= R0 + 15) {
            f32x4 sfr[4];
            #pragma unroll
            for (int fb = 0; fb < 4; ++fb) {
                f32x4 s = fz;
                #pragma unroll
                for (int kh = 0; kh < 2; ++kh) {
                    const f16x8 kfr = *(const f16x8*)&Ks[16 * fb + c][32 * kh + 8 * g];
                    s = __builtin_amdgcn_mfma_f32_16x16x32_f16(qf[kh], kfr, s, 0, 0, 0);
                }
                sfr[fb] = s;
            }

            if (kb + 63 > R0) {
                #pragma unroll
                for (int fb = 0; fb < 4; ++fb)
                    #pragma unroll
                    for (int r = 0; r < 4; ++r) {
                        const int rg = R0 + 4 * g + r;
                        const int cg = kb + 16 * fb + c;
                        if (cg > rg) sfr[fb][r] = -1e30f;
                    }
            }

            #pragma unroll
            for (int r = 0; r < 4; ++r) {
                float mx = fmaxf(fmaxf(sfr[0][r], sfr[1][r]), fmaxf(sfr[2][r], sfr[3][r]));
                mx = fmaxf(mx, __shfl_xor(mx, 1, 16));
                mx = fmaxf(mx, __shfl_xor(mx, 2, 16));
                mx = fmaxf(mx, __shfl_xor(mx, 4, 16));
                mx = fmaxf(mx, __shfl_xor(mx, 8, 16));
                const float mnew  = fmaxf(m_i[r], mx);
                const float alpha = __expf(m_i[r] - mnew);
                float p[4], rs = 0.f;
                #pragma unroll
                for (int fb = 0; fb < 4; ++fb) { p[fb] = __expf(sfr[fb][r] - mnew); rs += p[fb]; }
                rs += __shfl_xor(rs, 1, 16);
                rs += __shfl_xor(rs, 2, 16);
                rs += __shfl_xor(rs, 4, 16);
                rs += __shfl_xor(rs, 8, 16);
                l_i[r] = l_i[r] * alpha + rs;
                m_i[r] = mnew;
                #pragma unroll
                for (int fb = 0; fb < 4; ++fb) {
                    o_acc[fb][r] *= alpha;
                    Pf[w][4 * g + r][16 * fb + c] = (half_t)p[fb];
                }
            }

            asm volatile("s_waitcnt lgkmcnt(0)" ::: "memory");

            f16x8 pf[2];
            pf[0] = *(const f16x8*)&Pf[w][c][8 * g];
            pf[1] = *(const f16x8*)&Pf[w][c][32 + 8 * g];
            #pragma unroll
            for (int fb = 0; fb < 4; ++fb) {
                #pragma unroll
                for (int kh = 0; kh < 2; ++kh) {
                    const f16x8 vfr = *(const f16x8*)&Vt[16 * fb + c][32 * kh + 8 * g];
                    o_acc[fb] = __builtin_amdgcn_mfma_f32_16x16x32_f16(pf[kh], vfr, o_acc[fb], 0, 0, 0);
                }
            }
        }
    }

    const int b = bh >> 4;
    const int h = bh & 15;
    #pragma unroll
    for (int r = 0; r < 4; ++r) {
        const int t = qt2 * 128 + w * 16 + 4 * g + r;
        const float inv = 1.0f / l_i[r];
        #pragma unroll
        for (int fb = 0; fb < 4; ++fb) {
            const float val = o_acc[fb][r] * inv;
            short hi, lo;
            split1(val, hi, lo);
            const size_t idx = (size_t)(b * SEQ_T + t) * CDIM + h * HD + 16 * fb + c;
            AOh[idx] = hi;
            AOl[idx] = lo;
        }
    }
}

// ---------------------------------------------------------------------------
extern "C" void kernel_launch(void* const* d_in, const int* in_sizes, int n_in,
                              void* d_out, int out_size, void* d_ws, size_t ws_size,
                              hipStream_t stream) {
    (void)in_sizes; (void)n_in; (void)out_size; (void)ws_size;

    const float* x    = (const float*)d_in[0];
    const float* Wqkv = (const float*)d_in[2];
    const float* bqkv = (const float*)d_in[3];
    const float* Wo   = (const float*)d_in[4];
    const float* bo   = (const float*)d_in[5];
    float* out = (float*)d_out;

    // workspace layout — ~62 MB
    float* ws   = (float*)d_ws;
    float* cosT = ws;                               // 2048*64 f32
    float* sinT = cosT + SEQ_T * HD;
    const size_t QKV = (size_t)BH * SEQ_T * HD;     // 4.19M elements
    half_t* Qf  = (half_t*)(sinT + SEQ_T * HD);
    half_t* Kf  = Qf + QKV;
    half_t* Vf  = Kf + QKV;
    half_t* xf  = Vf + QKV;                         // [4096][1024] fp16
    half_t* Wqf = xf + (size_t)MROWS * CDIM;        // [3072][1024] fp16
    short* AOh  = (short*)(Wqf + (size_t)3 * CDIM * CDIM);   // [4096][1024] bf16 hi
    short* AOl  = AOh + (size_t)MROWS * CDIM;
    short* Wbh  = AOl + (size_t)MROWS * CDIM;       // [1024][1024] bf16 hi/lo (Wo)
    short* Wbl  = Wbh + (size_t)CDIM * CDIM;

    rope_table_kernel<<<SEQ_T, HD, 0, stream>>>(cosT, sinT);

    conv_half_kernel<<<1024, 256, 0, stream>>>(x, xf, MROWS * CDIM / 8);
    conv_half_kernel<<<1024, 256, 0, stream>>>(Wqkv, Wqf, 3 * CDIM * CDIM / 8);
    split_kernel<<<512, 256, 0, stream>>>(Wo, Wbh, Wbl, CDIM * CDIM / 8);

    // merged QKV projection (fp16): M=4096, N=3072, K=1024
    qkv_gemm_fp16_kernel<<<dim3(MROWS / 128, 3 * CDIM / 128), 256, 0, stream>>>(
        xf, Wqf, bqkv, cosT, sinT, Qf, Kf, Vf, MROWS, 3 * CDIM, CDIM);

    // causal flash attention (fp16 MFMA) — unchanged from round 5
    attn_mfma_kernel<<<dim3(BH, SEQ_T / 128), 512, 0, stream>>>(
        Qf, Kf, Vf, AOh, AOl);

    // output projection (bf16x3) — unchanged from round 5
    outproj_gemm_kernel<<<dim3(MROWS / 64, CDIM / 128), 256, 0, stream>>>(
        AOh, AOl, Wbh, Wbl, bo, out, MROWS, CDIM, CDIM);
}

// Round 11
// 226.247 us; speedup vs baseline: 4.4771x; 1.1108x over previous
//
#include <hip/hip_runtime.h>
#include <math.h>

// Problem constants: B=2, T=2048, C=1024, H=16, hd=64
#define SEQ_T 2048
#define CDIM 1024
#define HD 64
#define NH 16
#define NB 2
#define BH (NB * NH)          // 32
#define MROWS (NB * SEQ_T)    // 4096
#define LOG2E 1.4426950408889634f

typedef __attribute__((ext_vector_type(4))) float f32x4;
typedef _Float16 half_t;
typedef __attribute__((ext_vector_type(8))) _Float16 f16x8;
typedef __attribute__((ext_vector_type(4))) _Float16 f16x4;

// ---------------------------------------------------------------------------
// RoPE tables: cos[t][d] = cos(t * inv_freq[d%32]), inv_freq[i]=10000^(-2i/64)
// ---------------------------------------------------------------------------
__global__ void rope_table_kernel(float* __restrict__ cosT, float* __restrict__ sinT) {
    const int t = blockIdx.x;
    const int d = threadIdx.x;          // 0..63
    const int i = d & 31;
    const float inv = powf(10000.0f, -((float)(2 * i) / 64.0f));
    const float f = (float)t * inv;
    cosT[t * HD + d] = cosf(f);
    sinT[t * HD + d] = sinf(f);
}

// ---------------------------------------------------------------------------
// fp32 -> fp16 convert (RNE), vectorized
// ---------------------------------------------------------------------------
__global__ __launch_bounds__(256) void conv_half_kernel(
    const float* __restrict__ in, half_t* __restrict__ out, int n8)
{
    for (int i = blockIdx.x * blockDim.x + threadIdx.x; i < n8; i += gridDim.x * blockDim.x) {
        const float4 a = *(const float4*)(in + (size_t)i * 8);
        const float4 b = *(const float4*)(in + (size_t)i * 8 + 4);
        f16x8 o;
        o[0] = (half_t)a.x; o[1] = (half_t)a.y; o[2] = (half_t)a.z; o[3] = (half_t)a.w;
        o[4] = (half_t)b.x; o[5] = (half_t)b.y; o[6] = (half_t)b.z; o[7] = (half_t)b.w;
        *(f16x8*)(out + (size_t)i * 8) = o;
    }
}

// ---------------------------------------------------------------------------
// fp32 -> fp16 hi + fp16 lo (residual) split, ~21 mantissa bits combined
// ---------------------------------------------------------------------------
__global__ __launch_bounds__(256) void split_half_kernel(
    const float* __restrict__ in, half_t* __restrict__ hi, half_t* __restrict__ lo, int n8)
{
    for (int i = blockIdx.x * blockDim.x + threadIdx.x; i < n8; i += gridDim.x * blockDim.x) {
        float fv[8];
        *(float4*)&fv[0] = *(const float4*)(in + (size_t)i * 8);
        *(float4*)&fv[4] = *(const float4*)(in + (size_t)i * 8 + 4);
        f16x8 h, l;
        #pragma unroll
        for (int j = 0; j < 8; ++j) {
            const half_t hh = (half_t)fv[j];
            h[j] = hh;
            l[j] = (half_t)(fv[j] - (float)hh);
        }
        *(f16x8*)(hi + (size_t)i * 8) = h;
        *(f16x8*)(lo + (size_t)i * 8) = l;
    }
}

// ---------------------------------------------------------------------------
// fp16 MFMA QKV GEMM: qkv[m][n] = sum_k x[m][k]*Wqkv[n][k] + bias[n], N=3072.
// 128x128 tile, BK=32, 4 waves (2x2), wave = 64x64 (4x4 frags of 16x16x32).
// Epilogue: bias, RoPE Q/K (partner via shfl_xor 1), K scaled 0.125,
// Q scaled log2e (attn works in exp2 domain), fp16 out at [B*H][T][hd].
// ---------------------------------------------------------------------------
__global__ __launch_bounds__(256) void qkv_gemm_fp16_kernel(
    const half_t* __restrict__ Ag,    // [M][K] fp16 x
    const half_t* __restrict__ Bg,    // [N][K] fp16 Wqkv
    const float* __restrict__ bias,
    const float* __restrict__ cosT, const float* __restrict__ sinT,
    half_t* __restrict__ Qf, half_t* __restrict__ Kf, half_t* __restrict__ Vf,
    int M, int N, int K)
{
    __shared__ half_t As[128][40];   // [m][k]
    __shared__ half_t Bs[128][40];   // [n][k]

    const int tid  = threadIdx.x;
    const int row0 = blockIdx.x * 128;
    const int col0 = blockIdx.y * 128;
    const int lane = tid & 63;
    const int w    = tid >> 6;
    const int wr   = (w >> 1) * 64;
    const int wc   = (w & 1) * 64;
    const int g    = lane >> 4;
    const int c    = lane & 15;

    const int r0   = tid >> 2;          // 0..63
    const int col8 = (tid & 3) * 8;     // 0,8,16,24

    const half_t* pA0 = Ag + (size_t)(row0 + r0) * K + col8;
    const half_t* pA1 = pA0 + (size_t)64 * K;
    const half_t* pB0 = Bg + (size_t)(col0 + r0) * K + col8;
    const half_t* pB1 = pB0 + (size_t)64 * K;

    const f32x4 fz = {0.f, 0.f, 0.f, 0.f};
    f32x4 acc[4][4];
    #pragma unroll
    for (int i = 0; i < 4; ++i)
        #pragma unroll
        for (int j = 0; j < 4; ++j)
            acc[i][j] = fz;

    f16x8 sa0 = *(const f16x8*)(pA0);
    f16x8 sa1 = *(const f16x8*)(pA1);
    f16x8 sb0 = *(const f16x8*)(pB0);
    f16x8 sb1 = *(const f16x8*)(pB1);

    for (int k0 = 0; k0 < K; k0 += 32) {
        __syncthreads();
        *(f16x8*)&As[r0][col8]      = sa0;
        *(f16x8*)&As[r0 + 64][col8] = sa1;
        *(f16x8*)&Bs[r0][col8]      = sb0;
        *(f16x8*)&Bs[r0 + 64][col8] = sb1;
        if (k0 + 32 < K) {
            const int kn = k0 + 32;
            sa0 = *(const f16x8*)(pA0 + kn);
            sa1 = *(const f16x8*)(pA1 + kn);
            sb0 = *(const f16x8*)(pB0 + kn);
            sb1 = *(const f16x8*)(pB1 + kn);
        }
        __syncthreads();

        f16x8 af[4], bf[4];
        #pragma unroll
        for (int am = 0; am < 4; ++am)
            af[am] = *(const f16x8*)&As[wr + 16 * am + c][8 * g];
        #pragma unroll
        for (int bn = 0; bn < 4; ++bn)
            bf[bn] = *(const f16x8*)&Bs[wc + 16 * bn + c][8 * g];
        #pragma unroll
        for (int am = 0; am < 4; ++am)
            #pragma unroll
            for (int bn = 0; bn < 4; ++bn)
                acc[am][bn] = __builtin_amdgcn_mfma_f32_16x16x32_f16(af[am], bf[bn], acc[am][bn], 0, 0, 0);
    }

    #pragma unroll
    for (int am = 0; am < 4; ++am) {
        #pragma unroll
        for (int bn = 0; bn < 4; ++bn) {
            const int n   = col0 + wc + 16 * bn + c;   // 0..3071
            const int mat = n >> 10;                   // 0=Q 1=K 2=V
            const int h   = (n >> 6) & 15;
            const int d   = n & 63;
            const float bsv = bias[n];
            half_t* dst = (mat == 0) ? Qf : ((mat == 1) ? Kf : Vf);
            #pragma unroll
            for (int r = 0; r < 4; ++r) {
                const int m = row0 + wr + 16 * am + 4 * g + r;
                const int b = m >> 11;
                const int t = m & (SEQ_T - 1);
                const float v  = acc[am][bn][r] + bsv;
                const float vp = __shfl_xor(v, 1, 16);   // partner col n^1, same row
                float rv;
                if (mat == 2) {
                    rv = v;
                } else {
                    const float cs = cosT[t * HD + d], sn = sinT[t * HD + d];
                    rv = (d & 1) ? (v * cs + vp * sn) : (v * cs - vp * sn);
                    rv *= (mat == 1) ? 0.125f : LOG2E;   // fold 1/sqrt(hd) into K, log2e into Q
                }
                dst[(((size_t)(b * NH + h) * SEQ_T) + t) * HD + d] = (half_t)rv;
            }
        }
    }
}

// ---------------------------------------------------------------------------
// Out-projection: fp16 A (AO) x fp16-hi/lo B (Wo) -> 2 MFMA per frag pair.
// Y[m][n] = sum_k A[m][k]*W[n][k] + bias[n]; 64x128 tile, BK=32, 4 waves.
// ---------------------------------------------------------------------------
__global__ __launch_bounds__(256) void outproj_gemm_kernel(
    const half_t* __restrict__ Ag,                                  // [M][K]
    const half_t* __restrict__ Bhg, const half_t* __restrict__ Blg, // [N][K]
    const float* __restrict__ bias,
    float* __restrict__ Yo,
    int M, int N, int K)
{
    __shared__ half_t As[64][40];
    __shared__ half_t Bs_h[128][40], Bs_l[128][40];

    const int tid  = threadIdx.x;
    const int row0 = blockIdx.x * 64;
    const int col0 = blockIdx.y * 128;
    const int lane = tid & 63;
    const int w    = tid >> 6;
    const int wr   = (w >> 1) * 32;
    const int wc   = (w & 1) * 64;
    const int g    = lane >> 4;
    const int c    = lane & 15;

    const int r0   = tid >> 2;
    const int col8 = (tid & 3) * 8;

    const half_t* pA  = Ag  + (size_t)(row0 + r0) * K + col8;
    const half_t* pBh0 = Bhg + (size_t)(col0 + r0) * K + col8;
    const half_t* pBh1 = pBh0 + (size_t)64 * K;
    const half_t* pBl0 = Blg + (size_t)(col0 + r0) * K + col8;
    const half_t* pBl1 = pBl0 + (size_t)64 * K;

    const f32x4 fz = {0.f, 0.f, 0.f, 0.f};
    f32x4 acc[2][4];
    #pragma unroll
    for (int i = 0; i < 2; ++i)
        #pragma unroll
        for (int j = 0; j < 4; ++j)
            acc[i][j] = fz;

    f16x8 sa, sbh0, sbh1, sbl0, sbl1;
    sa   = *(const f16x8*)(pA);
    sbh0 = *(const f16x8*)(pBh0);
    sbh1 = *(const f16x8*)(pBh1);
    sbl0 = *(const f16x8*)(pBl0);
    sbl1 = *(const f16x8*)(pBl1);

    for (int k0 = 0; k0 < K; k0 += 32) {
        __syncthreads();
        *(f16x8*)&As[r0][col8]        = sa;
        *(f16x8*)&Bs_h[r0][col8]      = sbh0;
        *(f16x8*)&Bs_h[r0 + 64][col8] = sbh1;
        *(f16x8*)&Bs_l[r0][col8]      = sbl0;
        *(f16x8*)&Bs_l[r0 + 64][col8] = sbl1;
        if (k0 + 32 < K) {
            const int kn = k0 + 32;
            sa   = *(const f16x8*)(pA + kn);
            sbh0 = *(const f16x8*)(pBh0 + kn);
            sbh1 = *(const f16x8*)(pBh1 + kn);
            sbl0 = *(const f16x8*)(pBl0 + kn);
            sbl1 = *(const f16x8*)(pBl1 + kn);
        }
        __syncthreads();

        f16x8 af[2], bfh[4], bfl[4];
        #pragma unroll
        for (int am = 0; am < 2; ++am)
            af[am] = *(const f16x8*)&As[wr + 16 * am + c][8 * g];
        #pragma unroll
        for (int bn = 0; bn < 4; ++bn) {
            bfh[bn] = *(const f16x8*)&Bs_h[wc + 16 * bn + c][8 * g];
            bfl[bn] = *(const f16x8*)&Bs_l[wc + 16 * bn + c][8 * g];
        }
        #pragma unroll
        for (int am = 0; am < 2; ++am)
            #pragma unroll
            for (int bn = 0; bn < 4; ++bn) {
                acc[am][bn] = __builtin_amdgcn_mfma_f32_16x16x32_f16(af[am], bfh[bn], acc[am][bn], 0, 0, 0);
                acc[am][bn] = __builtin_amdgcn_mfma_f32_16x16x32_f16(af[am], bfl[bn], acc[am][bn], 0, 0, 0);
            }
    }

    #pragma unroll
    for (int am = 0; am < 2; ++am)
        #pragma unroll
        for (int bn = 0; bn < 4; ++bn) {
            const int n = col0 + wc + 16 * bn + c;
            const float bsv = bias[n];
            #pragma unroll
            for (int r = 0; r < 4; ++r) {
                const int m = row0 + wr + 16 * am + 4 * g + r;
                Yo[(size_t)m * N + n] = acc[am][bn][r] + bsv;
            }
        }
}

// ---------------------------------------------------------------------------
// Swapped-operand MFMA flash attention, fp16 operands, fp32 accum.
// Grid (bh=32, 16); block 512 = 8 waves; wave = 16-query strip.
// QK^T computed as mfma(K, Q): C/D row=key(4g+r), col=query(c) -> each lane's
// 16 S-values all belong to query q=R0+c. Softmax: in-lane reduce over 16 +
// 2 shfl_xor (masks 16/32) across the 4 g-lanes holding the same query.
// PV via 16x16x16 f16 MFMA: its k-map (k=4g+i) EQUALS the C/D row map, so P
// feeds the B-operand straight from registers — no LDS P, no shuffles.
// (sigma-invariant: A(V) and B(P) slots use the same (g,i)->key function.)
// O accumulates transposed (O^T[d][q]); per-lane scalar alpha rescale;
// epilogue transposes through a per-wave LDS region for coalesced stores.
// All exp in exp2-domain (log2e pre-folded into Q).
// ---------------------------------------------------------------------------
__global__ __launch_bounds__(512, 4) void attn_mfma_kernel(
    const half_t* __restrict__ Qf, const half_t* __restrict__ Kf,
    const half_t* __restrict__ Vf, half_t* __restrict__ AOf)
{
    __shared__ half_t Ks[64][72];       // [key][d]
    __shared__ half_t Vt[64][72];       // [d][key]

    const int bh  = blockIdx.x;
    const int qt2 = 15 - blockIdx.y;    // heavy blocks first
    const int tid = threadIdx.x;
    const int w    = tid >> 6;
    const int lane = tid & 63;
    const int g    = lane >> 4;
    const int c    = lane & 15;

    const int R0 = qt2 * 128 + w * 16;  // strip's first query row
    const size_t base = (size_t)bh * SEQ_T * HD;

    // Q fragments (B-operand): lane holds Q[R0+c][k=8g+i(+32kh)]
    f16x8 qf[2];
    {
        const half_t* qrow = Qf + base + (size_t)(R0 + c) * HD;
        qf[0] = *(const f16x8*)(qrow + 8 * g);
        qf[1] = *(const f16x8*)(qrow + 32 + 8 * g);
    }

    const f32x4 fz = {0.f, 0.f, 0.f, 0.f};
    f32x4 o_acc[4];                     // O^T[d=16fd+4g+r][q=R0+c]
    #pragma unroll
    for (int fd = 0; fd < 4; ++fd) o_acc[fd] = fz;
    float m_i = -1e30f, l_i = 0.f;      // per-query (per-lane, replicated x4 over g)

    // staging maps
    const int kr  = tid >> 3;           // K row 0..63
    const int kc8 = (tid & 7) * 8;
    const int kp  = tid & 31;           // V key pair
    const int d0  = (tid >> 5) * 4;     // V d chunk

    const int nt = 2 * qt2 + 2;

    f16x8 sk  = *(const f16x8*)(Kf + base + (size_t)kr * HD + kc8);
    f16x4 sv0 = *(const f16x4*)(Vf + base + (size_t)(2 * kp) * HD + d0);
    f16x4 sv1 = *(const f16x4*)(Vf + base + (size_t)(2 * kp + 1) * HD + d0);

    for (int kt = 0; kt < nt; ++kt) {
        __syncthreads();   // A: prior iteration's LDS reads complete
        *(f16x8*)&Ks[kr][kc8] = sk;
        #pragma unroll
        for (int j = 0; j < 4; ++j) {
            union { half_t h[2]; unsigned u; } pk;
            pk.h[0] = sv0[j]; pk.h[1] = sv1[j];
            *(unsigned*)&Vt[d0 + j][2 * kp] = pk.u;
        }
        if (kt + 1 < nt) {   // prefetch next tile under compute
            const int kb1 = (kt + 1) * 64;
            sk  = *(const f16x8*)(Kf + base + (size_t)(kb1 + kr) * HD + kc8);
            sv0 = *(const f16x4*)(Vf + base + (size_t)(kb1 + 2 * kp) * HD + d0);
            sv1 = *(const f16x4*)(Vf + base + (size_t)(kb1 + 2 * kp + 1) * HD + d0);
        }
        __syncthreads();   // B: staging visible

        const int kb = kt * 64;
        if (kb <= R0 + 15) {
            // ---- S^T = K Q^T: sfr[fb][r] = S'[key=kb+16fb+4g+r][q=R0+c] ----
            f32x4 sfr[4];
            #pragma unroll
            for (int fb = 0; fb < 4; ++fb) {
                f32x4 s = fz;
                #pragma unroll
                for (int kh = 0; kh < 2; ++kh) {
                    const f16x8 kfr = *(const f16x8*)&Ks[16 * fb + c][32 * kh + 8 * g];
                    s = __builtin_amdgcn_mfma_f32_16x16x32_f16(kfr, qf[kh], s, 0, 0, 0);
                }
                sfr[fb] = s;
            }

            // ---- causal mask (boundary tiles only) ----
            if (kb + 63 > R0) {
                const int qg = R0 + c;
                #pragma unroll
                for (int fb = 0; fb < 4; ++fb)
                    #pragma unroll
                    for (int r = 0; r < 4; ++r)
                        if (kb + 16 * fb + 4 * g + r > qg) sfr[fb][r] = -1e30f;
            }

            // ---- softmax: in-lane over 16 + 2 shfl across g-lanes ----
            float mx = fmaxf(fmaxf(sfr[0][0], sfr[0][1]), fmaxf(sfr[0][2], sfr[0][3]));
            #pragma unroll
            for (int fb = 1; fb < 4; ++fb)
                mx = fmaxf(mx, fmaxf(fmaxf(sfr[fb][0], sfr[fb][1]), fmaxf(sfr[fb][2], sfr[fb][3])));
            mx = fmaxf(mx, __shfl_xor(mx, 16));
            mx = fmaxf(mx, __shfl_xor(mx, 32));
            const float mnew  = fmaxf(m_i, mx);
            const float alpha = exp2f(m_i - mnew);
            float p[4][4];
            float rs = 0.f;
            #pragma unroll
            for (int fb = 0; fb < 4; ++fb)
                #pragma unroll
                for (int r = 0; r < 4; ++r) {
                    p[fb][r] = exp2f(sfr[fb][r] - mnew);
                    rs += p[fb][r];
                }
            rs += __shfl_xor(rs, 16);
            rs += __shfl_xor(rs, 32);
            l_i = l_i * alpha + rs;
            m_i = mnew;

            #pragma unroll
            for (int fd = 0; fd < 4; ++fd) o_acc[fd] *= alpha;

            // ---- P fragments: registers are ALREADY in 16x16x16 B-frag order ----
            f16x4 pf4[4];
            #pragma unroll
            for (int fb = 0; fb < 4; ++fb) {
                f16x4 t;
                t[0] = (half_t)p[fb][0]; t[1] = (half_t)p[fb][1];
                t[2] = (half_t)p[fb][2]; t[3] = (half_t)p[fb][3];
                pf4[fb] = t;
            }

            // ---- O^T += V^T P^T via 16x16x16 (A=V^T from Vt, B=P from regs) ----
            #pragma unroll
            for (int fd = 0; fd < 4; ++fd)
                #pragma unroll
                for (int fb = 0; fb < 4; ++fb) {
                    const f16x4 vfr = *(const f16x4*)&Vt[16 * fd + c][16 * fb + 4 * g];
                    o_acc[fd] = __builtin_amdgcn_mfma_f32_16x16x16f16(vfr, pf4[fb], o_acc[fd], 0, 0, 0);
                }
        }
    }

    // ---- epilogue: normalize, transpose via per-wave LDS region, store fp16 ----
    __syncthreads();   // all waves done reading Ks/Vt
    half_t* Ep = (w < 4) ? &Ks[16 * w][0] : &Vt[16 * (w - 4)][0];   // [16][72] region
    const float inv = 1.0f / l_i;
    #pragma unroll
    for (int fd = 0; fd < 4; ++fd)
        #pragma unroll
        for (int rp = 0; rp < 2; ++rp) {
            union { half_t h[2]; unsigned u; } pk;
            pk.h[0] = (half_t)(o_acc[fd][2 * rp]     * inv);
            pk.h[1] = (half_t)(o_acc[fd][2 * rp + 1] * inv);
            *(unsigned*)&Ep[c * 72 + 16 * fd + 4 * g + 2 * rp] = pk.u;   // [q=c][d]
        }
    asm volatile("s_waitcnt lgkmcnt(0)" ::: "memory");   // same-wave W->R ordering

    const int b = bh >> 4;
    const int h = bh & 15;
    const int rowr = lane >> 2;          // local query row 0..15
    const int dch  = (lane & 3) * 16;    // d chunk
    const f16x8 oa = *(const f16x8*)&Ep[rowr * 72 + dch];
    const f16x8 ob = *(const f16x8*)&Ep[rowr * 72 + dch + 8];
    half_t* dst = AOf + (size_t)(b * SEQ_T + R0 + rowr) * CDIM + h * HD + dch;
    *(f16x8*)(dst)     = oa;
    *(f16x8*)(dst + 8) = ob;
}

// ---------------------------------------------------------------------------
extern "C" void kernel_launch(void* const* d_in, const int* in_sizes, int n_in,
                              void* d_out, int out_size, void* d_ws, size_t ws_size,
                              hipStream_t stream) {
    (void)in_sizes; (void)n_in; (void)out_size; (void)ws_size;

    const float* x    = (const float*)d_in[0];
    const float* Wqkv = (const float*)d_in[2];
    const float* bqkv = (const float*)d_in[3];
    const float* Wo   = (const float*)d_in[4];
    const float* bo   = (const float*)d_in[5];
    float* out = (float*)d_out;

    // workspace layout — ~54 MB
    float* ws   = (float*)d_ws;
    float* cosT = ws;                               // 2048*64 f32
    float* sinT = cosT + SEQ_T * HD;
    const size_t QKV = (size_t)BH * SEQ_T * HD;     // 4.19M elements
    half_t* Qf  = (half_t*)(sinT + SEQ_T * HD);
    half_t* Kf  = Qf + QKV;
    half_t* Vf  = Kf + QKV;
    half_t* xf  = Vf + QKV;                         // [4096][1024] fp16
    half_t* Wqf = xf + (size_t)MROWS * CDIM;        // [3072][1024] fp16
    half_t* AOf = Wqf + (size_t)3 * CDIM * CDIM;    // [4096][1024] fp16
    half_t* Woh = AOf + (size_t)MROWS * CDIM;       // [1024][1024] fp16 hi
    half_t* Wol = Woh + (size_t)CDIM * CDIM;        // fp16 lo

    rope_table_kernel<<<SEQ_T, HD, 0, stream>>>(cosT, sinT);

    conv_half_kernel<<<1024, 256, 0, stream>>>(x, xf, MROWS * CDIM / 8);
    conv_half_kernel<<<1024, 256, 0, stream>>>(Wqkv, Wqf, 3 * CDIM * CDIM / 8);
    split_half_kernel<<<512, 256, 0, stream>>>(Wo, Woh, Wol, CDIM * CDIM / 8);

    // merged QKV projection (fp16): M=4096, N=3072, K=1024
    qkv_gemm_fp16_kernel<<<dim3(MROWS / 128, 3 * CDIM / 128), 256, 0, stream>>>(
        xf, Wqf, bqkv, cosT, sinT, Qf, Kf, Vf, MROWS, 3 * CDIM, CDIM);

    // causal flash attention (swapped-operand fp16 MFMA)
    attn_mfma_kernel<<<dim3(BH, SEQ_T / 128), 512, 0, stream>>>(
        Qf, Kf, Vf, AOf);

    // output projection (fp16 A x fp16-hi/lo B)
    outproj_gemm_kernel<<<dim3(MROWS / 64, CDIM / 128), 256, 0, stream>>>(
        AOf, Woh, Wol, bo, out, MROWS, CDIM, CDIM);
}

// Round 12
// 221.858 us; speedup vs baseline: 4.5657x; 1.0198x over previous
//
#include <hip/hip_runtime.h>
#include <math.h>

// Problem constants: B=2, T=2048, C=1024, H=16, hd=64
#define SEQ_T 2048
#define CDIM 1024
#define HD 64
#define NH 16
#define NB 2
#define BH (NB * NH)          // 32
#define MROWS (NB * SEQ_T)    // 4096
#define LOG2E 1.4426950408889634f

typedef __attribute__((ext_vector_type(4))) float f32x4;
typedef _Float16 half_t;
typedef __attribute__((ext_vector_type(8))) _Float16 f16x8;
typedef __attribute__((ext_vector_type(4))) _Float16 f16x4;

// async global->LDS, 16B per lane; LDS dest = wave-uniform base + lane*16
__device__ __forceinline__ void gload16(const half_t* g, half_t* l) {
    __builtin_amdgcn_global_load_lds(
        (const __attribute__((address_space(1))) void*)g,
        (__attribute__((address_space(3))) void*)l, 16, 0, 0);
}

// ---------------------------------------------------------------------------
// RoPE tables: cos[t][d] = cos(t * inv_freq[d%32]), inv_freq[i]=10000^(-2i/64)
// ---------------------------------------------------------------------------
__global__ void rope_table_kernel(float* __restrict__ cosT, float* __restrict__ sinT) {
    const int t = blockIdx.x;
    const int d = threadIdx.x;          // 0..63
    const int i = d & 31;
    const float inv = powf(10000.0f, -((float)(2 * i) / 64.0f));
    const float f = (float)t * inv;
    cosT[t * HD + d] = cosf(f);
    sinT[t * HD + d] = sinf(f);
}

// ---------------------------------------------------------------------------
// fp32 -> fp16 convert (RNE), vectorized
// ---------------------------------------------------------------------------
__global__ __launch_bounds__(256) void conv_half_kernel(
    const float* __restrict__ in, half_t* __restrict__ out, int n8)
{
    for (int i = blockIdx.x * blockDim.x + threadIdx.x; i < n8; i += gridDim.x * blockDim.x) {
        const float4 a = *(const float4*)(in + (size_t)i * 8);
        const float4 b = *(const float4*)(in + (size_t)i * 8 + 4);
        f16x8 o;
        o[0] = (half_t)a.x; o[1] = (half_t)a.y; o[2] = (half_t)a.z; o[3] = (half_t)a.w;
        o[4] = (half_t)b.x; o[5] = (half_t)b.y; o[6] = (half_t)b.z; o[7] = (half_t)b.w;
        *(f16x8*)(out + (size_t)i * 8) = o;
    }
}

// ---------------------------------------------------------------------------
// fp32 -> fp16 hi + fp16 lo (residual) split
// ---------------------------------------------------------------------------
__global__ __launch_bounds__(256) void split_half_kernel(
    const float* __restrict__ in, half_t* __restrict__ hi, half_t* __restrict__ lo, int n8)
{
    for (int i = blockIdx.x * blockDim.x + threadIdx.x; i < n8; i += gridDim.x * blockDim.x) {
        float fv[8];
        *(float4*)&fv[0] = *(const float4*)(in + (size_t)i * 8);
        *(float4*)&fv[4] = *(const float4*)(in + (size_t)i * 8 + 4);
        f16x8 h, l;
        #pragma unroll
        for (int j = 0; j < 8; ++j) {
            const half_t hh = (half_t)fv[j];
            h[j] = hh;
            l[j] = (half_t)(fv[j] - (float)hh);
        }
        *(f16x8*)(hi + (size_t)i * 8) = h;
        *(f16x8*)(lo + (size_t)i * 8) = l;
    }
}

// ---------------------------------------------------------------------------
// fp16 MFMA QKV GEMM with global_load_lds staging (m97 structure):
// unpadded LDS [128][32] halves, double-buffered, ONE barrier per K-step.
// LDS dest offset for lane l of wave w = 512*w + 8*l halves (= base + l*16B),
// matching row=16w+(l>>2), chunk=(l&3)*16B.
// Epilogue: bias, RoPE Q/K (partner via shfl_xor 1), K*0.125, Q*log2e.
// ---------------------------------------------------------------------------
__global__ __launch_bounds__(256) void qkv_gemm_fp16_kernel(
    const half_t* __restrict__ Ag,    // [M][K] fp16 x
    const half_t* __restrict__ Bg,    // [N][K] fp16 Wqkv
    const float* __restrict__ bias,
    const float* __restrict__ cosT, const float* __restrict__ sinT,
    half_t* __restrict__ Qf, half_t* __restrict__ Kf, half_t* __restrict__ Vf,
    int M, int N, int K)
{
    __shared__ half_t As[2][128 * 32];   // [buf][row*32 + colh], 8KB each
    __shared__ half_t Bs[2][128 * 32];

    const int tid  = threadIdx.x;
    const int row0 = blockIdx.x * 128;
    const int col0 = blockIdx.y * 128;
    const int lane = tid & 63;
    const int w    = tid >> 6;
    const int wr   = (w >> 1) * 64;
    const int wc   = (w & 1) * 64;
    const int g    = lane >> 4;
    const int c    = lane & 15;

    const int r0   = tid >> 2;          // 0..63
    const int col8 = (tid & 3) * 8;     // 0,8,16,24

    const half_t* pA0 = Ag + (size_t)(row0 + r0) * K + col8;
    const half_t* pA1 = pA0 + (size_t)64 * K;
    const half_t* pB0 = Bg + (size_t)(col0 + r0) * K + col8;
    const half_t* pB1 = pB0 + (size_t)64 * K;

    const int dst0 = w * 512 + lane * 8;   // halves; rows 0..63 region
    // rows 64..127 region: +2048 halves

    const f32x4 fz = {0.f, 0.f, 0.f, 0.f};
    f32x4 acc[4][4];
    #pragma unroll
    for (int i = 0; i < 4; ++i)
        #pragma unroll
        for (int j = 0; j < 4; ++j)
            acc[i][j] = fz;

    // prologue: stage k0=0 into buf 0
    gload16(pA0, &As[0][dst0]);
    gload16(pA1, &As[0][2048 + dst0]);
    gload16(pB0, &Bs[0][dst0]);
    gload16(pB1, &Bs[0][2048 + dst0]);

    int p = 0;
    for (int k0 = 0; k0 < K; k0 += 32, p ^= 1) {
        __syncthreads();   // drains vmcnt+lgkm: buf p ready, prior reads done
        if (k0 + 32 < K) {   // stage next slab into buf p^1 (in flight under MFMA)
            const int kn = k0 + 32;
            gload16(pA0 + kn, &As[p ^ 1][dst0]);
            gload16(pA1 + kn, &As[p ^ 1][2048 + dst0]);
            gload16(pB0 + kn, &Bs[p ^ 1][dst0]);
            gload16(pB1 + kn, &Bs[p ^ 1][2048 + dst0]);
        }
        f16x8 af[4], bf[4];
        #pragma unroll
        for (int am = 0; am < 4; ++am)
            af[am] = *(const f16x8*)&As[p][(wr + 16 * am + c) * 32 + 8 * g];
        #pragma unroll
        for (int bn = 0; bn < 4; ++bn)
            bf[bn] = *(const f16x8*)&Bs[p][(wc + 16 * bn + c) * 32 + 8 * g];
        #pragma unroll
        for (int am = 0; am < 4; ++am)
            #pragma unroll
            for (int bn = 0; bn < 4; ++bn)
                acc[am][bn] = __builtin_amdgcn_mfma_f32_16x16x32_f16(af[am], bf[bn], acc[am][bn], 0, 0, 0);
    }

    #pragma unroll
    for (int am = 0; am < 4; ++am) {
        #pragma unroll
        for (int bn = 0; bn < 4; ++bn) {
            const int n   = col0 + wc + 16 * bn + c;   // 0..3071
            const int mat = n >> 10;                   // 0=Q 1=K 2=V
            const int h   = (n >> 6) & 15;
            const int d   = n & 63;
            const float bsv = bias[n];
            half_t* dst = (mat == 0) ? Qf : ((mat == 1) ? Kf : Vf);
            #pragma unroll
            for (int r = 0; r < 4; ++r) {
                const int m = row0 + wr + 16 * am + 4 * g + r;
                const int b = m >> 11;
                const int t = m & (SEQ_T - 1);
                const float v  = acc[am][bn][r] + bsv;
                const float vp = __shfl_xor(v, 1, 16);   // partner col n^1, same row
                float rv;
                if (mat == 2) {
                    rv = v;
                } else {
                    const float cs = cosT[t * HD + d], sn = sinT[t * HD + d];
                    rv = (d & 1) ? (v * cs + vp * sn) : (v * cs - vp * sn);
                    rv *= (mat == 1) ? 0.125f : LOG2E;
                }
                dst[(((size_t)(b * NH + h) * SEQ_T) + t) * HD + d] = (half_t)rv;
            }
        }
    }
}

// ---------------------------------------------------------------------------
// Out-projection: fp16 A (AO) x fp16-hi/lo B (Wo) — unchanged (validated r11).
// ---------------------------------------------------------------------------
__global__ __launch_bounds__(256) void outproj_gemm_kernel(
    const half_t* __restrict__ Ag,
    const half_t* __restrict__ Bhg, const half_t* __restrict__ Blg,
    const float* __restrict__ bias,
    float* __restrict__ Yo,
    int M, int N, int K)
{
    __shared__ half_t As[64][40];
    __shared__ half_t Bs_h[128][40], Bs_l[128][40];

    const int tid  = threadIdx.x;
    const int row0 = blockIdx.x * 64;
    const int col0 = blockIdx.y * 128;
    const int lane = tid & 63;
    const int w    = tid >> 6;
    const int wr   = (w >> 1) * 32;
    const int wc   = (w & 1) * 64;
    const int g    = lane >> 4;
    const int c    = lane & 15;

    const int r0   = tid >> 2;
    const int col8 = (tid & 3) * 8;

    const half_t* pA  = Ag  + (size_t)(row0 + r0) * K + col8;
    const half_t* pBh0 = Bhg + (size_t)(col0 + r0) * K + col8;
    const half_t* pBh1 = pBh0 + (size_t)64 * K;
    const half_t* pBl0 = Blg + (size_t)(col0 + r0) * K + col8;
    const half_t* pBl1 = pBl0 + (size_t)64 * K;

    const f32x4 fz = {0.f, 0.f, 0.f, 0.f};
    f32x4 acc[2][4];
    #pragma unroll
    for (int i = 0; i < 2; ++i)
        #pragma unroll
        for (int j = 0; j < 4; ++j)
            acc[i][j] = fz;

    f16x8 sa, sbh0, sbh1, sbl0, sbl1;
    sa   = *(const f16x8*)(pA);
    sbh0 = *(const f16x8*)(pBh0);
    sbh1 = *(const f16x8*)(pBh1);
    sbl0 = *(const f16x8*)(pBl0);
    sbl1 = *(const f16x8*)(pBl1);

    for (int k0 = 0; k0 < K; k0 += 32) {
        __syncthreads();
        *(f16x8*)&As[r0][col8]        = sa;
        *(f16x8*)&Bs_h[r0][col8]      = sbh0;
        *(f16x8*)&Bs_h[r0 + 64][col8] = sbh1;
        *(f16x8*)&Bs_l[r0][col8]      = sbl0;
        *(f16x8*)&Bs_l[r0 + 64][col8] = sbl1;
        if (k0 + 32 < K) {
            const int kn = k0 + 32;
            sa   = *(const f16x8*)(pA + kn);
            sbh0 = *(const f16x8*)(pBh0 + kn);
            sbh1 = *(const f16x8*)(pBh1 + kn);
            sbl0 = *(const f16x8*)(pBl0 + kn);
            sbl1 = *(const f16x8*)(pBl1 + kn);
        }
        __syncthreads();

        f16x8 af[2], bfh[4], bfl[4];
        #pragma unroll
        for (int am = 0; am < 2; ++am)
            af[am] = *(const f16x8*)&As[wr + 16 * am + c][8 * g];
        #pragma unroll
        for (int bn = 0; bn < 4; ++bn) {
            bfh[bn] = *(const f16x8*)&Bs_h[wc + 16 * bn + c][8 * g];
            bfl[bn] = *(const f16x8*)&Bs_l[wc + 16 * bn + c][8 * g];
        }
        #pragma unroll
        for (int am = 0; am < 2; ++am)
            #pragma unroll
            for (int bn = 0; bn < 4; ++bn) {
                acc[am][bn] = __builtin_amdgcn_mfma_f32_16x16x32_f16(af[am], bfh[bn], acc[am][bn], 0, 0, 0);
                acc[am][bn] = __builtin_amdgcn_mfma_f32_16x16x32_f16(af[am], bfl[bn], acc[am][bn], 0, 0, 0);
            }
    }

    #pragma unroll
    for (int am = 0; am < 2; ++am)
        #pragma unroll
        for (int bn = 0; bn < 4; ++bn) {
            const int n = col0 + wc + 16 * bn + c;
            const float bsv = bias[n];
            #pragma unroll
            for (int r = 0; r < 4; ++r) {
                const int m = row0 + wr + 16 * am + 4 * g + r;
                Yo[(size_t)m * N + n] = acc[am][bn][r] + bsv;
            }
        }
}

// ---------------------------------------------------------------------------
// Swapped-operand MFMA flash attention, fp16 operands, fp32 accum.
// KVBLK=128: one barrier pair + ONE online-softmax update per 128 keys.
// Grid (bh=32, 16); block 512 = 8 waves; wave = 16-query strip.
// QK^T via mfma(K, Q): lane holds 32 S-values of query q=R0+c (8 fb x 4 r).
// PV via 16x16x16: P feeds B-operand straight from registers (k-map == C/D
// row map, sigma-invariant). O accumulates transposed; LDS-transpose epilogue.
// ---------------------------------------------------------------------------
__global__ __launch_bounds__(512, 4) void attn_mfma_kernel(
    const half_t* __restrict__ Qf, const half_t* __restrict__ Kf,
    const half_t* __restrict__ Vf, half_t* __restrict__ AOf)
{
    __shared__ half_t Ks[128][72];      // [key][d]
    __shared__ half_t Vt[64][136];      // [d][key 0..127]

    const int bh  = blockIdx.x;
    const int qt2 = 15 - blockIdx.y;    // heavy blocks first
    const int tid = threadIdx.x;
    const int w    = tid >> 6;
    const int lane = tid & 63;
    const int g    = lane >> 4;
    const int c    = lane & 15;

    const int R0 = qt2 * 128 + w * 16;  // strip's first query row
    const size_t base = (size_t)bh * SEQ_T * HD;

    // Q fragments (B-operand): lane holds Q[R0+c][k=8g+i(+32kh)]
    f16x8 qf[2];
    {
        const half_t* qrow = Qf + base + (size_t)(R0 + c) * HD;
        qf[0] = *(const f16x8*)(qrow + 8 * g);
        qf[1] = *(const f16x8*)(qrow + 32 + 8 * g);
    }

    const f32x4 fz = {0.f, 0.f, 0.f, 0.f};
    f32x4 o_acc[4];                     // O^T[d=16fd+4g+r][q=R0+c]
    #pragma unroll
    for (int fd = 0; fd < 4; ++fd) o_acc[fd] = fz;
    float m_i = -1e30f, l_i = 0.f;

    // staging maps (128-key tile)
    const int kr  = tid >> 2;           // K row 0..127
    const int kc8 = (tid & 3) * 8;      // K col chunk (halves); second at +32
    const int kp  = tid & 63;           // V key pair 0..63
    const int d0  = (tid >> 6) * 8;     // V d chunk = w*8

    const int nt = qt2 + 1;             // 128-key tiles

    // prologue: stage regs for kt=0
    f16x8 sk0 = *(const f16x8*)(Kf + base + (size_t)kr * HD + kc8);
    f16x8 sk1 = *(const f16x8*)(Kf + base + (size_t)kr * HD + kc8 + 32);
    f16x8 sv0 = *(const f16x8*)(Vf + base + (size_t)(2 * kp) * HD + d0);
    f16x8 sv1 = *(const f16x8*)(Vf + base + (size_t)(2 * kp + 1) * HD + d0);

    for (int kt = 0; kt < nt; ++kt) {
        __syncthreads();   // A: prior tile's LDS reads complete
        *(f16x8*)&Ks[kr][kc8]      = sk0;
        *(f16x8*)&Ks[kr][kc8 + 32] = sk1;
        #pragma unroll
        for (int j = 0; j < 8; ++j) {
            union { half_t h[2]; unsigned u; } pk;
            pk.h[0] = sv0[j]; pk.h[1] = sv1[j];
            *(unsigned*)&Vt[d0 + j][2 * kp] = pk.u;
        }
        if (kt + 1 < nt) {   // prefetch next 128-key tile under compute
            const int kb1 = (kt + 1) * 128;
            sk0 = *(const f16x8*)(Kf + base + (size_t)(kb1 + kr) * HD + kc8);
            sk1 = *(const f16x8*)(Kf + base + (size_t)(kb1 + kr) * HD + kc8 + 32);
            sv0 = *(const f16x8*)(Vf + base + (size_t)(kb1 + 2 * kp) * HD + d0);
            sv1 = *(const f16x8*)(Vf + base + (size_t)(kb1 + 2 * kp + 1) * HD + d0);
        }
        __syncthreads();   // B: staging visible

        const int kb = kt * 128;

        // ---- S^T: sfr[fb][r] = S'[key=kb+16fb+4g+r][q=R0+c], fb=0..7 ----
        f32x4 sfr[8];
        #pragma unroll
        for (int fb = 0; fb < 8; ++fb) {
            f32x4 s = fz;
            #pragma unroll
            for (int kh = 0; kh < 2; ++kh) {
                const f16x8 kfr = *(const f16x8*)&Ks[16 * fb + c][32 * kh + 8 * g];
                s = __builtin_amdgcn_mfma_f32_16x16x32_f16(kfr, qf[kh], s, 0, 0, 0);
            }
            sfr[fb] = s;
        }

        // ---- causal mask (final tile only) ----
        if (kt == nt - 1) {
            const int qg = R0 + c;
            #pragma unroll
            for (int fb = 0; fb < 8; ++fb)
                #pragma unroll
                for (int r = 0; r < 4; ++r)
                    if (kb + 16 * fb + 4 * g + r > qg) sfr[fb][r] = -1e30f;
        }

        // ---- ONE online-softmax update per 128 keys ----
        float mx = -1e30f;
        #pragma unroll
        for (int fb = 0; fb < 8; ++fb)
            mx = fmaxf(mx, fmaxf(fmaxf(sfr[fb][0], sfr[fb][1]), fmaxf(sfr[fb][2], sfr[fb][3])));
        mx = fmaxf(mx, __shfl_xor(mx, 16));
        mx = fmaxf(mx, __shfl_xor(mx, 32));
        const float mnew  = fmaxf(m_i, mx);
        const float alpha = exp2f(m_i - mnew);
        float p[8][4];
        float rs = 0.f;
        #pragma unroll
        for (int fb = 0; fb < 8; ++fb)
            #pragma unroll
            for (int r = 0; r < 4; ++r) {
                p[fb][r] = exp2f(sfr[fb][r] - mnew);
                rs += p[fb][r];
            }
        rs += __shfl_xor(rs, 16);
        rs += __shfl_xor(rs, 32);
        l_i = l_i * alpha + rs;
        m_i = mnew;

        #pragma unroll
        for (int fd = 0; fd < 4; ++fd) o_acc[fd] *= alpha;

        // ---- P fragments in registers (B-operand order) ----
        f16x4 pf4[8];
        #pragma unroll
        for (int fb = 0; fb < 8; ++fb) {
            f16x4 t;
            t[0] = (half_t)p[fb][0]; t[1] = (half_t)p[fb][1];
            t[2] = (half_t)p[fb][2]; t[3] = (half_t)p[fb][3];
            pf4[fb] = t;
        }

        // ---- O^T += V^T P^T via 16x16x16 ----
        #pragma unroll
        for (int fd = 0; fd < 4; ++fd)
            #pragma unroll
            for (int fb = 0; fb < 8; ++fb) {
                const f16x4 vfr = *(const f16x4*)&Vt[16 * fd + c][16 * fb + 4 * g];
                o_acc[fd] = __builtin_amdgcn_mfma_f32_16x16x16f16(vfr, pf4[fb], o_acc[fd], 0, 0, 0);
            }
    }

    // ---- epilogue: normalize, transpose via per-wave LDS region, store ----
    __syncthreads();   // all waves done reading Ks/Vt
    half_t* Ep = &Ks[16 * w][0];        // [16][72] per-wave region (8x16=128 rows)
    const float inv = 1.0f / l_i;
    #pragma unroll
    for (int fd = 0; fd < 4; ++fd)
        #pragma unroll
        for (int rp = 0; rp < 2; ++rp) {
            union { half_t h[2]; unsigned u; } pk;
            pk.h[0] = (half_t)(o_acc[fd][2 * rp]     * inv);
            pk.h[1] = (half_t)(o_acc[fd][2 * rp + 1] * inv);
            *(unsigned*)&Ep[c * 72 + 16 * fd + 4 * g + 2 * rp] = pk.u;   // [q=c][d]
        }
    asm volatile("s_waitcnt lgkmcnt(0)" ::: "memory");   // same-wave W->R ordering

    const int b = bh >> 4;
    const int h = bh & 15;
    const int rowr = lane >> 2;          // local query row 0..15
    const int dch  = (lane & 3) * 16;    // d chunk
    const f16x8 oa = *(const f16x8*)&Ep[rowr * 72 + dch];
    const f16x8 ob = *(const f16x8*)&Ep[rowr * 72 + dch + 8];
    half_t* dst = AOf + (size_t)(b * SEQ_T + R0 + rowr) * CDIM + h * HD + dch;
    *(f16x8*)(dst)     = oa;
    *(f16x8*)(dst + 8) = ob;
}

// ---------------------------------------------------------------------------
extern "C" void kernel_launch(void* const* d_in, const int* in_sizes, int n_in,
                              void* d_out, int out_size, void* d_ws, size_t ws_size,
                              hipStream_t stream) {
    (void)in_sizes; (void)n_in; (void)out_size; (void)ws_size;

    const float* x    = (const float*)d_in[0];
    const float* Wqkv = (const float*)d_in[2];
    const float* bqkv = (const float*)d_in[3];
    const float* Wo   = (const float*)d_in[4];
    const float* bo   = (const float*)d_in[5];
    float* out = (float*)d_out;

    // workspace layout — ~54 MB
    float* ws   = (float*)d_ws;
    float* cosT = ws;                               // 2048*64 f32
    float* sinT = cosT + SEQ_T * HD;
    const size_t QKV = (size_t)BH * SEQ_T * HD;     // 4.19M elements
    half_t* Qf  = (half_t*)(sinT + SEQ_T * HD);
    half_t* Kf  = Qf + QKV;
    half_t* Vf  = Kf + QKV;
    half_t* xf  = Vf + QKV;                         // [4096][1024] fp16
    half_t* Wqf = xf + (size_t)MROWS * CDIM;        // [3072][1024] fp16
    half_t* AOf = Wqf + (size_t)3 * CDIM * CDIM;    // [4096][1024] fp16
    half_t* Woh = AOf + (size_t)MROWS * CDIM;       // [1024][1024] fp16 hi
    half_t* Wol = Woh + (size_t)CDIM * CDIM;        // fp16 lo

    rope_table_kernel<<<SEQ_T, HD, 0, stream>>>(cosT, sinT);

    conv_half_kernel<<<1024, 256, 0, stream>>>(x, xf, MROWS * CDIM / 8);
    conv_half_kernel<<<1024, 256, 0, stream>>>(Wqkv, Wqf, 3 * CDIM * CDIM / 8);
    split_half_kernel<<<512, 256, 0, stream>>>(Wo, Woh, Wol, CDIM * CDIM / 8);

    // merged QKV projection (fp16, global_load_lds): M=4096, N=3072, K=1024
    qkv_gemm_fp16_kernel<<<dim3(MROWS / 128, 3 * CDIM / 128), 256, 0, stream>>>(
        xf, Wqf, bqkv, cosT, sinT, Qf, Kf, Vf, MROWS, 3 * CDIM, CDIM);

    // causal flash attention (swapped-operand fp16 MFMA, KVBLK=128)
    attn_mfma_kernel<<<dim3(BH, SEQ_T / 128), 512, 0, stream>>>(
        Qf, Kf, Vf, AOf);

    // output projection (fp16 A x fp16-hi/lo B)
    outproj_gemm_kernel<<<dim3(MROWS / 64, CDIM / 128), 256, 0, stream>>>(
        AOf, Woh, Wol, bo, out, MROWS, CDIM, CDIM);
}